// Round 8
// baseline (403.106 us; speedup 1.0000x reference)
//
#include <hip/hip_runtime.h>
#include <math.h>

#define BB   64
#define HWP  1024
#define SS   512
#define DD   256
#define TAU_INV (1.0f/0.07f)
#define SIGMA   (1.0f/1024.0f)

typedef unsigned short us;
typedef __attribute__((ext_vector_type(8))) short short8v;
typedef __attribute__((ext_vector_type(8))) unsigned short ushort8v;
typedef __attribute__((ext_vector_type(4))) float floatx4;

__device__ __forceinline__ float bf2f(us u) {
    return __uint_as_float((unsigned)u << 16);
}
__device__ __forceinline__ us f2bf(float f) {
    unsigned u = __float_as_uint(f);
    u += 0x7FFFu + ((u >> 16) & 1u);
    return (us)(u >> 16);
}
__device__ __forceinline__ void split_bf(float v, us& h, us& l) {
    h = f2bf(v);
    l = f2bf(v - bf2f(h));
}

// R15: HBM->LDS DMA, bypasses VGPRs entirely (regalloc cannot sink it).
__device__ __forceinline__ void dma16(const us* g, us* l) {
    __builtin_amdgcn_global_load_lds(
        (const __attribute__((address_space(1))) unsigned int*)g,
        (__attribute__((address_space(3))) unsigned int*)l, 16, 0, 0);
}

__global__ void zero_out_k(float* out) { if (threadIdx.x == 0) out[0] = 0.0f; }

// =====================  MFMA GEMM  =====================
// C[m,n] = sum_k A(m,k)*B(n,k). Tile 128 x NT, BK=32, 16x16x32 bf16 MFMA.
// R15: G4'/G8 DMA pipeline (global_load_lds, dbuf, counted vmcnt) — worked.
// R17: G6 hybrid DMA (transpose prepass + dma B) — worked, left top-5.
// R18: G1 resurfaced at 52us (R16's occupancy fix was a null on time — the
//      reg-staged loop stalls regardless of occupancy; 4th confirmation).
//      Every DMA'd kernel left the top-5 => convert G1/G2 too:
//      conversion hoisted to prepasses (convsplit_img_k transposes+splits img
//      to [b][p][c] h/l planes; convsplit_row_k splits text), then DMA=3:
//      full-DMA 4-plane pipeline (Ah/Al/Bh/Bl), NT=128, dbuf, vmcnt(4).
//      Same split values, same MFMA order (ah*bh, ah*bl, al*bh), same
//      k-order, same epilogue -> bitwise-identical output.
enum { OPM_F32_ROW = 0, OPM_F32_COL = 1, OPM_SPL_ROW = 2, OPM_SPL_COL = 3,
       OPM_B16_COL = 4, OPM_B16_ROW = 5, OPM_WGT_COL = 6, OPM_WGT_ROW = 7 };
enum { OUT_F32 = 0, OUT_B16 = 1 };

#define LDSTRIDE 40

template<int MODE, int ROWS, int NW>
struct SRegs {
    static constexpr int RR = ROWS / 128;
    static constexpr bool ISF32 = (MODE == OPM_F32_ROW) || (MODE == OPM_F32_COL);
    ushort8v h[ISF32 ? 1 : RR][2];
    ushort8v l[(MODE == OPM_SPL_ROW) ? RR : 1][2];
    float4   f[ISF32 ? RR : 1][4];
};

// global -> registers (raw data, no conversion math)
template<int MODE, int ROWS, int NW>
__device__ __forceinline__ void stage_load(
    const char* p0, const char* p1, int ld, int row0, int k0, int tid,
    SRegs<MODE, ROWS, NW>& R)
{
    #pragma unroll
    for (int rr = 0; rr < ROWS / 128; ++rr) {
        if constexpr (MODE == OPM_SPL_ROW) {
            const us* ph = (const us*)p0;
            const us* pl = (const us*)p1;
            if constexpr (NW == 4) {
                const int i = rr * 128 + (tid >> 1), ko = (tid & 1) * 16;
                const long long g = (long long)(row0 + i) * ld + k0 + ko;
                R.h[rr][0] = *(const ushort8v*)&ph[g];
                R.h[rr][1] = *(const ushort8v*)&ph[g + 8];
                R.l[rr][0] = *(const ushort8v*)&pl[g];
                R.l[rr][1] = *(const ushort8v*)&pl[g + 8];
            } else {
                const int i = rr * 128 + (tid >> 2), ko = (tid & 3) * 8;
                const long long g = (long long)(row0 + i) * ld + k0 + ko;
                R.h[rr][0] = *(const ushort8v*)&ph[g];
                R.l[rr][0] = *(const ushort8v*)&pl[g];
            }
        } else if constexpr (MODE == OPM_B16_ROW || MODE == OPM_WGT_ROW) {
            const us* ph = (const us*)p0;
            if constexpr (NW == 4) {
                const int i = rr * 128 + (tid >> 1), ko = (tid & 1) * 16;
                const long long g = (long long)(row0 + i) * ld + k0 + ko;
                R.h[rr][0] = *(const ushort8v*)&ph[g];
                R.h[rr][1] = *(const ushort8v*)&ph[g + 8];
            } else {
                const int i = rr * 128 + (tid >> 2), ko = (tid & 3) * 8;
                const long long g = (long long)(row0 + i) * ld + k0 + ko;
                R.h[rr][0] = *(const ushort8v*)&ph[g];
            }
        } else if constexpr (MODE == OPM_F32_ROW) {
            const float* pf = (const float*)p0;
            if constexpr (NW == 4) {
                const int i = rr * 128 + (tid >> 1), ko = (tid & 1) * 16;
                const long long g = (long long)(row0 + i) * ld + k0 + ko;
                #pragma unroll
                for (int c = 0; c < 4; ++c)
                    R.f[rr][c] = *(const float4*)&pf[g + c * 4];
            } else {
                const int i = rr * 128 + (tid >> 2), ko = (tid & 3) * 8;
                const long long g = (long long)(row0 + i) * ld + k0 + ko;
                R.f[rr][0] = *(const float4*)&pf[g];
                R.f[rr][1] = *(const float4*)&pf[g + 4];
            }
        } else if constexpr (MODE == OPM_F32_COL) {
            const float* pf = (const float*)p0;
            if constexpr (NW == 4) {
                const int m = rr * 128 + (tid & 127), kh = (tid >> 7) * 16;
                const long long base = (long long)(k0 + kh) * ld + row0 + m;
                #pragma unroll
                for (int c = 0; c < 4; ++c) {
                    float4 v;
                    v.x = pf[base + (long long)(c * 4 + 0) * ld];
                    v.y = pf[base + (long long)(c * 4 + 1) * ld];
                    v.z = pf[base + (long long)(c * 4 + 2) * ld];
                    v.w = pf[base + (long long)(c * 4 + 3) * ld];
                    R.f[rr][c] = v;
                }
            } else {
                const int m = rr * 128 + (tid & 127), kh = (tid >> 7) * 8;
                const long long base = (long long)(k0 + kh) * ld + row0 + m;
                #pragma unroll
                for (int c = 0; c < 2; ++c) {
                    float4 v;
                    v.x = pf[base + (long long)(c * 4 + 0) * ld];
                    v.y = pf[base + (long long)(c * 4 + 1) * ld];
                    v.z = pf[base + (long long)(c * 4 + 2) * ld];
                    v.w = pf[base + (long long)(c * 4 + 3) * ld];
                    R.f[rr][c] = v;
                }
            }
        } else if constexpr (MODE == OPM_B16_COL) {
            const us* ph = (const us*)p0;
            if constexpr (NW == 4) {
                const int m = rr * 128 + (tid & 127), kh = (tid >> 7) * 16;
                const long long base = (long long)(k0 + kh) * ld + row0 + m;
                #pragma unroll
                for (int kk = 0; kk < 8; ++kk) {
                    R.h[rr][0][kk] = ph[base + (long long)kk * ld];
                    R.h[rr][1][kk] = ph[base + (long long)(kk + 8) * ld];
                }
            } else {
                const int m = rr * 128 + (tid & 127), kh = (tid >> 7) * 8;
                const long long base = (long long)(k0 + kh) * ld + row0 + m;
                #pragma unroll
                for (int kk = 0; kk < 8; ++kk)
                    R.h[rr][0][kk] = ph[base + (long long)kk * ld];
            }
        }
    }
}

// registers -> LDS (conversion / weight math happens here)
template<int MODE, int ROWS, int NW>
__device__ __forceinline__ void stage_store(
    const SRegs<MODE, ROWS, NW>& R, us* ldsH, us* ldsL, int tid, float nlo, float inv)
{
    #pragma unroll
    for (int rr = 0; rr < ROWS / 128; ++rr) {
        if constexpr (MODE == OPM_SPL_ROW) {
            if constexpr (NW == 4) {
                const int i = rr * 128 + (tid >> 1), ko = (tid & 1) * 16;
                *(ushort8v*)&ldsH[i * LDSTRIDE + ko]     = R.h[rr][0];
                *(ushort8v*)&ldsH[i * LDSTRIDE + ko + 8] = R.h[rr][1];
                *(ushort8v*)&ldsL[i * LDSTRIDE + ko]     = R.l[rr][0];
                *(ushort8v*)&ldsL[i * LDSTRIDE + ko + 8] = R.l[rr][1];
            } else {
                const int i = rr * 128 + (tid >> 2), ko = (tid & 3) * 8;
                *(ushort8v*)&ldsH[i * LDSTRIDE + ko] = R.h[rr][0];
                *(ushort8v*)&ldsL[i * LDSTRIDE + ko] = R.l[rr][0];
            }
        } else if constexpr (MODE == OPM_B16_ROW) {
            if constexpr (NW == 4) {
                const int i = rr * 128 + (tid >> 1), ko = (tid & 1) * 16;
                *(ushort8v*)&ldsH[i * LDSTRIDE + ko]     = R.h[rr][0];
                *(ushort8v*)&ldsH[i * LDSTRIDE + ko + 8] = R.h[rr][1];
            } else {
                const int i = rr * 128 + (tid >> 2), ko = (tid & 3) * 8;
                *(ushort8v*)&ldsH[i * LDSTRIDE + ko] = R.h[rr][0];
            }
        } else if constexpr (MODE == OPM_WGT_ROW) {
            const int i = tid >> 2, ko = (tid & 3) * 8;
            us v[8];
            #pragma unroll
            for (int j = 0; j < 8; ++j) {
                const float w0 = fmaf(bf2f(R.h[0][0][j]), inv, nlo);
                v[j] = (w0 < SIGMA) ? (us)0 : f2bf(w0);
            }
            *(ushort8v*)&ldsH[i * LDSTRIDE + ko] = *(const ushort8v*)&v[0];
        } else if constexpr (MODE == OPM_F32_ROW) {
            if constexpr (NW == 4) {
                const int i = rr * 128 + (tid >> 1), ko = (tid & 1) * 16;
                us h16[16], l16a[16];
                #pragma unroll
                for (int c = 0; c < 4; ++c) {
                    float4 v = R.f[rr][c];
                    split_bf(v.x, h16[c*4+0], l16a[c*4+0]);
                    split_bf(v.y, h16[c*4+1], l16a[c*4+1]);
                    split_bf(v.z, h16[c*4+2], l16a[c*4+2]);
                    split_bf(v.w, h16[c*4+3], l16a[c*4+3]);
                }
                *(ushort8v*)&ldsH[i * LDSTRIDE + ko]     = *(const ushort8v*)&h16[0];
                *(ushort8v*)&ldsH[i * LDSTRIDE + ko + 8] = *(const ushort8v*)&h16[8];
                *(ushort8v*)&ldsL[i * LDSTRIDE + ko]     = *(const ushort8v*)&l16a[0];
                *(ushort8v*)&ldsL[i * LDSTRIDE + ko + 8] = *(const ushort8v*)&l16a[8];
            } else {
                const int i = rr * 128 + (tid >> 2), ko = (tid & 3) * 8;
                us h8[8], l8[8];
                #pragma unroll
                for (int c = 0; c < 2; ++c) {
                    float4 v = R.f[rr][c];
                    split_bf(v.x, h8[c*4+0], l8[c*4+0]);
                    split_bf(v.y, h8[c*4+1], l8[c*4+1]);
                    split_bf(v.z, h8[c*4+2], l8[c*4+2]);
                    split_bf(v.w, h8[c*4+3], l8[c*4+3]);
                }
                *(ushort8v*)&ldsH[i * LDSTRIDE + ko] = *(const ushort8v*)&h8[0];
                *(ushort8v*)&ldsL[i * LDSTRIDE + ko] = *(const ushort8v*)&l8[0];
            }
        } else if constexpr (MODE == OPM_F32_COL) {
            if constexpr (NW == 4) {
                const int m = rr * 128 + (tid & 127), kh = (tid >> 7) * 16;
                us vh[16], vl[16];
                #pragma unroll
                for (int c = 0; c < 4; ++c) {
                    float4 v = R.f[rr][c];
                    split_bf(v.x, vh[c*4+0], vl[c*4+0]);
                    split_bf(v.y, vh[c*4+1], vl[c*4+1]);
                    split_bf(v.z, vh[c*4+2], vl[c*4+2]);
                    split_bf(v.w, vh[c*4+3], vl[c*4+3]);
                }
                *(ushort8v*)&ldsH[m * LDSTRIDE + kh]     = *(const ushort8v*)&vh[0];
                *(ushort8v*)&ldsH[m * LDSTRIDE + kh + 8] = *(const ushort8v*)&vh[8];
                *(ushort8v*)&ldsL[m * LDSTRIDE + kh]     = *(const ushort8v*)&vl[0];
                *(ushort8v*)&ldsL[m * LDSTRIDE + kh + 8] = *(const ushort8v*)&vl[8];
            } else {
                const int m = rr * 128 + (tid & 127), kh = (tid >> 7) * 8;
                us vh[8], vl[8];
                #pragma unroll
                for (int c = 0; c < 2; ++c) {
                    float4 v = R.f[rr][c];
                    split_bf(v.x, vh[c*4+0], vl[c*4+0]);
                    split_bf(v.y, vh[c*4+1], vl[c*4+1]);
                    split_bf(v.z, vh[c*4+2], vl[c*4+2]);
                    split_bf(v.w, vh[c*4+3], vl[c*4+3]);
                }
                *(ushort8v*)&ldsH[m * LDSTRIDE + kh] = *(const ushort8v*)&vh[0];
                *(ushort8v*)&ldsL[m * LDSTRIDE + kh] = *(const ushort8v*)&vl[0];
            }
        } else if constexpr (MODE == OPM_B16_COL) {
            if constexpr (NW == 4) {
                const int m = rr * 128 + (tid & 127), kh = (tid >> 7) * 16;
                us v[16];
                #pragma unroll
                for (int kk = 0; kk < 16; ++kk)
                    v[kk] = (kk < 8) ? R.h[rr][0][kk & 7] : R.h[rr][1][kk & 7];
                *(ushort8v*)&ldsH[m * LDSTRIDE + kh]     = *(const ushort8v*)&v[0];
                *(ushort8v*)&ldsH[m * LDSTRIDE + kh + 8] = *(const ushort8v*)&v[8];
            } else {
                const int m = rr * 128 + (tid & 127), kh = (tid >> 7) * 8;
                *(ushort8v*)&ldsH[m * LDSTRIDE + kh] = R.h[rr][0];
            }
        }
    }
}

template<int AMODE, int BMODE, int OMODE, int EPI, int NT, int PREF, int NW, int DMA>
__global__ __launch_bounds__(NW * 64) void mfma_gemm(
    const void* A0, const void* A1, const void* B0, const void* B1, void* C0,
    int M, int N, int K, int lda, int ldb, int ldc,
    long long sA, long long sB, long long sC,
    const float* __restrict__ bias, const float* __restrict__ invm,
    const float* __restrict__ invn, float scale,
    const float* __restrict__ wlo, const float* __restrict__ whi,
    float* __restrict__ aux0, float* __restrict__ aux1,
    float* __restrict__ aux2, float* __restrict__ aux3, float* __restrict__ aux4)
{
    constexpr bool ASPL = (AMODE <= OPM_SPL_COL);
    constexpr bool BSPL = (BMODE <= OPM_SPL_COL);
    constexpr int NF = NT / 16;
    constexpr int MI = 8 / NW;         // 16-row frags per wave (2 @NW4, 1 @NW8)
    constexpr int RPW = 128 / NW;      // rows per wave
    __shared__ __align__(16) us Ah[(DMA == 1 || DMA == 3) ? 8 : 128 * LDSTRIDE];
    __shared__ __align__(16) us Al[(!DMA && ASPL) ? 128 * LDSTRIDE : 8];
    __shared__ __align__(16) us Bh[DMA ? 8 : NT * LDSTRIDE];
    __shared__ __align__(16) us Bl[(!DMA && BSPL) ? NT * LDSTRIDE : 8];
    __shared__ __align__(16) us AhD[(DMA == 1 || DMA == 3) ? 2 * 128 * 32 : 8];
    __shared__ __align__(16) us BhD[DMA ? 2 * NT * 32 : 8];
    __shared__ __align__(16) us AlD[(DMA == 3) ? 2 * 128 * 32 : 8];
    __shared__ __align__(16) us BlD[(DMA == 3) ? 2 * NT * 32 : 8];
    __shared__ float redm[(EPI == 4) ? NW * NT : 1];
    __shared__ float reds[(EPI == 4) ? NW * NT : 1];

    const int tid = threadIdx.x;
    const int w = tid >> 6, lane = tid & 63;
    const int quad = lane >> 4, l16 = lane & 15;

    // XCD-chunked bijective swizzle (nwg % 8 == 0 for all grids here).
    int bx = blockIdx.x, by = blockIdx.y, bz = blockIdx.z;
    {
        const int nbx = gridDim.x, nby = gridDim.y, nbz = gridDim.z;
        const int nwg = nbx * nby * nbz;
        if ((nwg & 7) == 0) {
            const int hw = bx + nbx * (by + nby * bz);
            const int cpx = nwg >> 3;
            int wk = (hw & 7) * cpx + (hw >> 3);
            bx = wk % nbx; wk /= nbx;
            by = wk % nby; bz = wk / nby;
        }
    }

    const int m0 = bx * 128, n0 = by * NT;
    const int b = bz;

    const char* Ab0 = (const char*)A0 + (long long)b * sA;
    const char* Ab1 = A1 ? (const char*)A1 + (long long)b * sA : nullptr;
    const char* Bb0 = (const char*)B0 + (long long)b * sB;
    const char* Bb1 = B1 ? (const char*)B1 + (long long)b * sB : nullptr;

    floatx4 acc[MI][NF];
    #pragma unroll
    for (int mi = 0; mi < MI; ++mi)
        #pragma unroll
        for (int ni = 0; ni < NF; ++ni)
            acc[mi][ni] = (floatx4){0.f, 0.f, 0.f, 0.f};

    if constexpr (DMA == 1) {
        // ================= R15a: DMA-staged pipeline (ROW/ROW) ==============
        const us* Abu = (const us*)Ab0;
        const us* Bbu = (const us*)Bb0;
        const int drow = 16 * w + (lane >> 2);
        const int dcol = (lane & 3) * 8;
        const us* aS = Abu + (long long)(m0 + drow) * lda + dcol;
        const us* bS = Bbu + (long long)(n0 + drow) * ldb + dcol;
        us* aD = &AhD[0] + 512 * w;
        us* bD = &BhD[0] + 512 * w;
        const int NTL = K >> 5;

        dma16(aS,      aD);
        dma16(bS,      bD);
        dma16(aS + 32, aD + 128 * 32);
        dma16(bS + 32, bD + NT * 32);

        int cur = 0;
        for (int t = 0; t < NTL; ++t) {
            if (t + 1 == NTL) asm volatile("s_waitcnt vmcnt(0)" ::: "memory");
            else              asm volatile("s_waitcnt vmcnt(2)" ::: "memory");
            __builtin_amdgcn_s_barrier();
            asm volatile("" ::: "memory");

            {
                const us* Ac = &AhD[cur * 128 * 32];
                const us* Bc = &BhD[cur * NT * 32];
                short8v ah = *(const short8v*)&Ac[(16 * w + l16) * 32 + quad * 8];
                #pragma unroll
                for (int ni = 0; ni < NF; ++ni) {
                    short8v bh = *(const short8v*)&Bc[(16 * ni + l16) * 32 + quad * 8];
                    acc[0][ni] = __builtin_amdgcn_mfma_f32_16x16x32_bf16(ah, bh, acc[0][ni], 0, 0, 0);
                }
            }

            asm volatile("" ::: "memory");
            __builtin_amdgcn_s_barrier();
            if (t + 2 < NTL) {
                const long long off = (long long)(t + 2) * 32;
                dma16(aS + off, aD + cur * 128 * 32);
                dma16(bS + off, bD + cur * NT * 32);
            }
            cur ^= 1;
        }
    } else if constexpr (DMA == 2) {
        // ===== R17: hybrid — A reg-staged (WGT transform), B DMA-staged =====
        const us* Abu = (const us*)Ab0;   // simT
        const us* Bbu = (const us*)Bb0;   // patchesT
        const float* wloA = wlo + (long long)b * M;
        const float* whiA = whi + (long long)b * M;
        const int ai = tid >> 2, ako = (tid & 3) * 8;
        const float lo = wloA[m0 + ai];
        const float invA = 1.0f / (whiA[m0 + ai] - lo + 1e-8f);
        const float nloA = -lo * invA;

        const int rB = 16 * w + (lane >> 2);
        const us* bS = Bbu + (long long)(n0 + rB) * ldb + (lane & 3) * 8;
        us* bD = &BhD[0] + 512 * w;
        const long long aRow = (long long)(m0 + ai) * lda + ako;
        const int NTL = K >> 5;

        dma16(bS, bD);                                   // B(0) first
        ushort8v ra = *(const ushort8v*)&Abu[aRow];      // A(0)
        dma16(bS + 32, bD + 4096);                       // B(1)

        int cur = 0;
        for (int t = 0; t < NTL; ++t) {
            us v[8];
            #pragma unroll
            for (int j = 0; j < 8; ++j) {
                const float w0 = fmaf(bf2f(ra[j]), invA, nloA);
                v[j] = (w0 < SIGMA) ? (us)0 : f2bf(w0);
            }
            *(ushort8v*)&Ah[ai * LDSTRIDE + ako] = *(const ushort8v*)&v[0];
            asm volatile("s_waitcnt vmcnt(1) lgkmcnt(0)" ::: "memory");
            __builtin_amdgcn_s_barrier();

            if (t + 1 < NTL)
                ra = *(const ushort8v*)&Abu[aRow + (long long)(t + 1) * 32];

            {
                const us* Bc = &BhD[cur * 4096];
                short8v ah = *(const short8v*)&Ah[(16 * w + l16) * LDSTRIDE + quad * 8];
                #pragma unroll
                for (int ni = 0; ni < NF; ++ni) {
                    short8v bh = *(const short8v*)&Bc[(16 * ni + l16) * 32 + quad * 8];
                    acc[0][ni] = __builtin_amdgcn_mfma_f32_16x16x32_bf16(ah, bh, acc[0][ni], 0, 0, 0);
                }
            }
            asm volatile("" ::: "memory");
            __builtin_amdgcn_s_barrier();
            if (t + 2 < NTL)
                dma16(bS + (long long)(t + 2) * 32, bD + cur * 4096);
            cur ^= 1;
        }
    } else if constexpr (DMA == 3) {
        // ===== R18: full-DMA 4-plane split pipeline (NT must be 128) ========
        // A = (Ah,Al) planes [M][K] row-major; B = (Bh,Bl) planes [N][K].
        // Per thread per k-tile: 4 dma16. MFMA order per ni: ah*bh, ah*bl,
        // al*bh — identical to the reg-staged split path (bitwise-equal C).
        const us* AhU = (const us*)Ab0;
        const us* AlU = (const us*)Ab1;
        const us* BhU = (const us*)Bb0;
        const us* BlU = (const us*)Bb1;
        const int drow = 16 * w + (lane >> 2);
        const int dcol = (lane & 3) * 8;
        const us* aHS = AhU + (long long)(m0 + drow) * lda + dcol;
        const us* aLS = AlU + (long long)(m0 + drow) * lda + dcol;
        const us* bHS = BhU + (long long)(n0 + drow) * ldb + dcol;
        const us* bLS = BlU + (long long)(n0 + drow) * ldb + dcol;
        us* aHDp = &AhD[0] + 512 * w;
        us* aLDp = &AlD[0] + 512 * w;
        us* bHDp = &BhD[0] + 512 * w;
        us* bLDp = &BlD[0] + 512 * w;
        const int NTL = K >> 5;

        dma16(aHS, aHDp); dma16(aLS, aLDp); dma16(bHS, bHDp); dma16(bLS, bLDp);
        dma16(aHS + 32, aHDp + 4096); dma16(aLS + 32, aLDp + 4096);
        dma16(bHS + 32, bHDp + 4096); dma16(bLS + 32, bLDp + 4096);

        int cur = 0;
        for (int t = 0; t < NTL; ++t) {
            if (t + 1 == NTL) asm volatile("s_waitcnt vmcnt(0)" ::: "memory");
            else              asm volatile("s_waitcnt vmcnt(4)" ::: "memory");
            __builtin_amdgcn_s_barrier();
            asm volatile("" ::: "memory");

            {
                const us* Ach = &AhD[cur * 4096];
                const us* Acl = &AlD[cur * 4096];
                const us* Bch = &BhD[cur * 4096];
                const us* Bcl = &BlD[cur * 4096];
                const int ra = (16 * w + l16) * 32 + quad * 8;
                short8v ah = *(const short8v*)&Ach[ra];
                short8v al = *(const short8v*)&Acl[ra];
                #pragma unroll
                for (int ni = 0; ni < NF; ++ni) {
                    const int rb = (16 * ni + l16) * 32 + quad * 8;
                    short8v bh = *(const short8v*)&Bch[rb];
                    short8v bl = *(const short8v*)&Bcl[rb];
                    acc[0][ni] = __builtin_amdgcn_mfma_f32_16x16x32_bf16(ah, bh, acc[0][ni], 0, 0, 0);
                    acc[0][ni] = __builtin_amdgcn_mfma_f32_16x16x32_bf16(ah, bl, acc[0][ni], 0, 0, 0);
                    acc[0][ni] = __builtin_amdgcn_mfma_f32_16x16x32_bf16(al, bh, acc[0][ni], 0, 0, 0);
                }
            }

            asm volatile("" ::: "memory");
            __builtin_amdgcn_s_barrier();
            if (t + 2 < NTL) {
                const long long off = (long long)(t + 2) * 32;
                dma16(aHS + off, aHDp + cur * 4096);
                dma16(aLS + off, aLDp + cur * 4096);
                dma16(bHS + off, bHDp + cur * 4096);
                dma16(bLS + off, bLDp + cur * 4096);
            }
            cur ^= 1;
        }
    } else {
        // ================= reg-staged path ==================================
        float nloA = 0.f, invA = 0.f;
        if constexpr (AMODE == OPM_WGT_ROW) {
            const float* wloA = wlo + (long long)b * M;
            const float* whiA = whi + (long long)b * M;
            const int row = m0 + (tid >> 2);
            const float lo = wloA[row];
            invA = 1.0f / (whiA[row] - lo + 1e-8f);
            nloA = -lo * invA;
        }

        SRegs<AMODE, 128, NW> RA0, RA1;
        SRegs<BMODE, NT, NW>  RB0, RB1;
        if constexpr (PREF) {
            stage_load<AMODE, 128, NW>(Ab0, Ab1, lda, m0, 0, tid, RA0);
            stage_load<BMODE, NT, NW>(Bb0, Bb1, ldb, n0, 0, tid, RB0);
            stage_load<AMODE, 128, NW>(Ab0, Ab1, lda, m0, 32, tid, RA1);
            stage_load<BMODE, NT, NW>(Bb0, Bb1, ldb, n0, 32, tid, RB1);
        }

        auto do_mfma = [&]() {
            short8v ah[MI], al[MI];
            #pragma unroll
            for (int mi = 0; mi < MI; ++mi) {
                const int r = (RPW * w + 16 * mi + l16) * LDSTRIDE + quad * 8;
                ah[mi] = *(const short8v*)&Ah[r];
                if constexpr (ASPL) al[mi] = *(const short8v*)&Al[r];
            }
            #pragma unroll
            for (int ni = 0; ni < NF; ++ni) {
                const int rB = (16 * ni + l16) * LDSTRIDE + quad * 8;
                short8v bh = *(const short8v*)&Bh[rB];
                #pragma unroll
                for (int mi = 0; mi < MI; ++mi)
                    acc[mi][ni] = __builtin_amdgcn_mfma_f32_16x16x32_bf16(ah[mi], bh, acc[mi][ni], 0, 0, 0);
                if constexpr (BSPL) {
                    short8v bl = *(const short8v*)&Bl[rB];
                    #pragma unroll
                    for (int mi = 0; mi < MI; ++mi)
                        acc[mi][ni] = __builtin_amdgcn_mfma_f32_16x16x32_bf16(ah[mi], bl, acc[mi][ni], 0, 0, 0);
                }
                if constexpr (ASPL) {
                    #pragma unroll
                    for (int mi = 0; mi < MI; ++mi)
                        acc[mi][ni] = __builtin_amdgcn_mfma_f32_16x16x32_bf16(al[mi], bh, acc[mi][ni], 0, 0, 0);
                }
            }
        };

#define GEMM_SUBSTEP(RAx, RBx, KCUR, KNEXT)                                    \
    do {                                                                       \
        if constexpr (!PREF) {                                                 \
            stage_load<AMODE, 128, NW>(Ab0, Ab1, lda, m0, (KCUR), tid, RAx);   \
            stage_load<BMODE, NT, NW>(Bb0, Bb1, ldb, n0, (KCUR), tid, RBx);    \
        }                                                                      \
        stage_store<AMODE, 128, NW>(RAx, Ah, Al, tid, nloA, invA);             \
        stage_store<BMODE, NT, NW>(RBx, Bh, Bl, tid, 0.f, 0.f);                \
        if constexpr (PREF) {                                                  \
            asm volatile("s_waitcnt lgkmcnt(0)" ::: "memory");                 \
            __builtin_amdgcn_s_barrier();                                      \
            if ((KNEXT) < K) {                                                 \
                stage_load<AMODE, 128, NW>(Ab0, Ab1, lda, m0, (KNEXT), tid, RAx); \
                stage_load<BMODE, NT, NW>(Bb0, Bb1, ldb, n0, (KNEXT), tid, RBx);  \
            }                                                                  \
        } else {                                                               \
            __syncthreads();                                                   \
        }                                                                      \
        do_mfma();                                                             \
        if constexpr (PREF) {                                                  \
            asm volatile("s_waitcnt lgkmcnt(0)" ::: "memory");                 \
            __builtin_amdgcn_s_barrier();                                      \
        } else {                                                               \
            __syncthreads();                                                   \
        }                                                                      \
    } while (0)

        for (int k0 = 0; k0 < K; k0 += 64) {
            GEMM_SUBSTEP(RA0, RB0, k0, k0 + 64);
            GEMM_SUBSTEP(RA1, RB1, k0 + 32, k0 + 96);
        }
#undef GEMM_SUBSTEP
    }

    if constexpr (EPI != 4) {
        char* Cb0 = (char*)C0 + (long long)b * sC;
        #pragma unroll
        for (int mi = 0; mi < MI; ++mi)
            #pragma unroll
            for (int ni = 0; ni < NF; ++ni)
                #pragma unroll
                for (int r = 0; r < 4; ++r) {
                    const int row = m0 + RPW * w + 16 * mi + quad * 4 + r;
                    const int col = n0 + 16 * ni + l16;
                    float v = acc[mi][ni][r];
                    if constexpr (EPI == 1) v += bias[col];
                    const long long idx = (long long)row * ldc + col;
                    if constexpr (OMODE == OUT_F32) ((float*)Cb0)[idx] = v;
                    else                            ((us*)Cb0)[idx] = f2bf(v);
                }
    }

    if constexpr (EPI == 3) {
        // ROW min/max of bf16-rounded stored values (C is simT[s][p]).
        #pragma unroll
        for (int r = 0; r < 4; ++r) {
            const int grow = m0 + RPW * w + quad * 4 + r;
            float lo = 1e30f, hi = -1e30f;
            #pragma unroll
            for (int ni = 0; ni < NF; ++ni) {
                const float vr = bf2f(f2bf(acc[0][ni][r]));
                lo = fminf(lo, vr); hi = fmaxf(hi, vr);
            }
            lo = fminf(lo, __shfl_xor(lo, 1)); hi = fmaxf(hi, __shfl_xor(hi, 1));
            lo = fminf(lo, __shfl_xor(lo, 2)); hi = fmaxf(hi, __shfl_xor(hi, 2));
            lo = fminf(lo, __shfl_xor(lo, 4)); hi = fmaxf(hi, __shfl_xor(hi, 4));
            lo = fminf(lo, __shfl_xor(lo, 8)); hi = fmaxf(hi, __shfl_xor(hi, 8));
            if (l16 == 0) {
                const long long o = ((long long)b * M + grow) * 8 + by;
                aux0[o] = lo; aux1[o] = hi;
            }
        }
    }

    if constexpr (EPI == 4) {
        // f_sim never stored: emit row/col LSE partials + diagonal.
        float bn[NF];
        #pragma unroll
        for (int ni = 0; ni < NF; ++ni)
            bn[ni] = invn[(long long)b * N + n0 + 16 * ni + l16] * scale;
        float amv[MI * 4];
        #pragma unroll
        for (int mi = 0; mi < MI; ++mi)
            #pragma unroll
            for (int r = 0; r < 4; ++r)
                amv[mi * 4 + r] = invm[(long long)b * M + m0 + RPW * w + 16 * mi + quad * 4 + r];

        // row pass
        #pragma unroll
        for (int mi = 0; mi < MI; ++mi)
            #pragma unroll
            for (int r = 0; r < 4; ++r) {
                const int grow = m0 + RPW * w + 16 * mi + quad * 4 + r;
                float vv[NF];
                float rm = -1e30f;
                #pragma unroll
                for (int ni = 0; ni < NF; ++ni) {
                    const float v = acc[mi][ni][r] * amv[mi * 4 + r] * bn[ni];
                    vv[ni] = v;
                    rm = fmaxf(rm, v);
                    if (grow == n0 + 16 * ni + l16)
                        aux4[(long long)b * M + grow] = v;
                }
                #pragma unroll
                for (int o = 8; o > 0; o >>= 1) rm = fmaxf(rm, __shfl_xor(rm, o));
                float rs = 0.f;
                #pragma unroll
                for (int ni = 0; ni < NF; ++ni) rs += expf(vv[ni] - rm);
                #pragma unroll
                for (int o = 8; o > 0; o >>= 1) rs += __shfl_xor(rs, o);
                if (l16 == 0) {
                    const long long o = ((long long)b * M + grow) * 4 + by;
                    aux0[o] = rm; aux1[o] = rs;
                }
            }

        // col pass
        #pragma unroll
        for (int ni = 0; ni < NF; ++ni) {
            float va[MI * 4];
            float cm = -1e30f;
            #pragma unroll
            for (int mi = 0; mi < MI; ++mi)
                #pragma unroll
                for (int r = 0; r < 4; ++r) {
                    const float v = acc[mi][ni][r] * amv[mi * 4 + r] * bn[ni];
                    va[mi * 4 + r] = v;
                    cm = fmaxf(cm, v);
                }
            cm = fmaxf(cm, __shfl_xor(cm, 16));
            cm = fmaxf(cm, __shfl_xor(cm, 32));
            float cs = 0.f;
            #pragma unroll
            for (int j = 0; j < MI * 4; ++j) cs += expf(va[j] - cm);
            cs += __shfl_xor(cs, 16);
            cs += __shfl_xor(cs, 32);
            if (quad == 0) {
                redm[w * NT + 16 * ni + l16] = cm;
                reds[w * NT + 16 * ni + l16] = cs;
            }
        }
        __syncthreads();
        if (tid < NT) {
            float m = -1e30f, s = 0.f;
            #pragma unroll
            for (int w4 = 0; w4 < NW; ++w4) {
                const float cm = redm[w4 * NT + tid], cs = reds[w4 * NT + tid];
                const float nm = fmaxf(m, cm);
                s = s * expf(m - nm) + cs * expf(cm - nm);
                m = nm;
            }
            const long long o = ((long long)b * N + n0 + tid) * 4 + bx;
            aux2[o] = m; aux3[o] = s;
        }
    }
}

// =====================  small kernels  =====================

// R17: patchesT[b][d][p] = patches[b][p][d]; 64x64 LDS tiles.
__global__ __launch_bounds__(256) void transpose_k(
    const us* __restrict__ src, us* __restrict__ dst)
{
    __shared__ us t[64][66];
    const int b = blockIdx.z;
    const int p0 = blockIdx.x * 64, d0 = blockIdx.y * 64;
    const us* s = src + (long long)b * 262144;
    us* d = dst + (long long)b * 262144;
    const int r = threadIdx.x >> 3, c8 = (threadIdx.x & 7) * 8;
    #pragma unroll
    for (int h = 0; h < 64; h += 32)
        *(ushort8v*)&t[r + h][c8] =
            *(const ushort8v*)&s[(long long)(p0 + r + h) * 256 + d0 + c8];
    __syncthreads();
    #pragma unroll
    for (int h = 0; h < 64; h += 32) {
        us v[8];
        #pragma unroll
        for (int j = 0; j < 8; ++j) v[j] = t[c8 + j][r + h];
        *(ushort8v*)&d[(long long)(d0 + r + h) * 1024 + p0 + c8] =
            *(const ushort8v*)&v[0];
    }
}

// R18: imgTH/imgTL[b][p][c] = split_bf(img[b][c][p]) — transpose + split.
__global__ __launch_bounds__(256) void convsplit_img_k(
    const float* __restrict__ img, us* __restrict__ th, us* __restrict__ tl)
{
    __shared__ float t[64][65];
    const int b = blockIdx.z;
    const int p0 = blockIdx.x * 64, c0 = blockIdx.y * 64;
    const float* s = img + (long long)b * 262144;
    const int r = threadIdx.x >> 4, c4 = (threadIdx.x & 15) * 4;
    #pragma unroll
    for (int h = 0; h < 64; h += 16) {
        float4 v = *(const float4*)&s[(long long)(c0 + r + h) * 1024 + p0 + c4];
        t[r + h][c4 + 0] = v.x; t[r + h][c4 + 1] = v.y;
        t[r + h][c4 + 2] = v.z; t[r + h][c4 + 3] = v.w;
    }
    __syncthreads();
    #pragma unroll
    for (int h = 0; h < 64; h += 16) {
        const int p = h + r;
        us vh[4], vl[4];
        #pragma unroll
        for (int j = 0; j < 4; ++j)
            split_bf(t[c4 + j][p], vh[j], vl[j]);
        const long long o = (long long)b * 262144 + (long long)(p0 + p) * 256 + c0 + c4;
        *(ushort4*)&th[o] = *(const ushort4*)&vh[0];
        *(ushort4*)&tl[o] = *(const ushort4*)&vl[0];
    }
}

// R18: row-major f32 -> split bf16 planes (text).
__global__ __launch_bounds__(256) void convsplit_row_k(
    const float* __restrict__ x, us* __restrict__ th, us* __restrict__ tl)
{
    const long long i = ((long long)blockIdx.x * 256 + threadIdx.x) * 4;
    float4 v = *(const float4*)&x[i];
    us vh[4], vl[4];
    split_bf(v.x, vh[0], vl[0]); split_bf(v.y, vh[1], vl[1]);
    split_bf(v.z, vh[2], vl[2]); split_bf(v.w, vh[3], vl[3]);
    *(ushort4*)&th[i] = *(const ushort4*)&vh[0];
    *(ushort4*)&tl[i] = *(const ushort4*)&vl[0];
}

__global__ __launch_bounds__(256) void convert_w_k(
    const float* Wv, const float* Wt, us* Wvh, us* Wvl, us* Wth, us* Wtl)
{
    const int i = blockIdx.x * 256 + threadIdx.x;
    split_bf(Wv[i], Wvh[i], Wvl[i]);
    split_bf(Wt[i], Wth[i], Wtl[i]);
}

__global__ __launch_bounds__(256) void mean_img_k(
    const float* __restrict__ img, float* __restrict__ mimg)
{
    const int row = blockIdx.x * 4 + (threadIdx.x >> 6);
    const int lane = threadIdx.x & 63;
    const float* p = img + (long long)row * 1024;
    float s = 0.f;
    #pragma unroll
    for (int c = 0; c < 4; ++c) {
        float4 v = *(const float4*)&p[(c * 64 + lane) * 4];
        s += v.x + v.y + v.z + v.w;
    }
    #pragma unroll
    for (int o = 32; o > 0; o >>= 1) s += __shfl_xor(s, o);
    if (lane == 0) mimg[row] = s * (1.0f / 1024.0f);
}

__global__ __launch_bounds__(256) void mean_text_s1(
    const float* __restrict__ text, float* __restrict__ part)
{
    const int b = blockIdx.x, ch = blockIdx.y, k = threadIdx.x;
    const float* p = text + ((long long)b * 512 + ch * 64) * 256 + k;
    float s = 0.f;
    for (int r = 0; r < 64; ++r) s += p[r * 256];
    part[(b * 8 + ch) * 256 + k] = s;
}
__global__ __launch_bounds__(256) void mean_text_s2(
    const float* __restrict__ part, float* __restrict__ mt)
{
    const int b = blockIdx.x, k = threadIdx.x;
    float s = 0.f;
    for (int c = 0; c < 8; ++c) s += part[(b * 8 + c) * 256 + k];
    mt[b * 256 + k] = s * (1.0f / 512.0f);
}

__global__ __launch_bounds__(256) void small_adapter_k(
    const float* __restrict__ x, const float* __restrict__ W,
    const float* __restrict__ bias, float* __restrict__ y)
{
    const int b = blockIdx.x, d = threadIdx.x;
    __shared__ float xs[256];
    xs[d] = x[b * 256 + d];
    __syncthreads();
    const float4* w = (const float4*)(W + (long long)d * 256);
    const float4* xv = (const float4*)xs;
    float s = bias[d];
    #pragma unroll 8
    for (int k = 0; k < 64; ++k) {
        const float4 a = xv[k], ww = w[k];
        s += a.x * ww.x + a.y * ww.y + a.z * ww.z + a.w * ww.w;
    }
    y[b * 256 + d] = s;
}

// ---- parallelized global loss ----

__global__ __launch_bounds__(256) void inv_norm_f32_k(
    const float* __restrict__ x, float* __restrict__ inv)
{
    const int row = blockIdx.x * 4 + (threadIdx.x >> 6);
    const int lane = threadIdx.x & 63;
    float4 v = *(const float4*)&x[(long long)row * 256 + lane * 4];
    float s = v.x * v.x + v.y * v.y + v.z * v.z + v.w * v.w;
    #pragma unroll
    for (int o = 32; o > 0; o >>= 1) s += __shfl_xor(s, o);
    if (lane == 0) inv[row] = 1.0f / fmaxf(sqrtf(s), 1e-8f);
}

__global__ __launch_bounds__(256) void g_sim_k(
    const float* __restrict__ gi, const float* __restrict__ gt,
    const float* __restrict__ invI, const float* __restrict__ invT,
    float* __restrict__ gs)
{
    const int i = blockIdx.x, t = threadIdx.x;
    const int j = t >> 2, part = t & 3;
    __shared__ float a[256];
    a[t] = gi[i * 256 + t];
    __syncthreads();
    const float* bp = gt + (long long)j * 256 + part * 64;
    const float* ap = a + part * 64;
    float s = 0.f;
    #pragma unroll 16
    for (int k = 0; k < 64; ++k) s += ap[k] * bp[k];
    s += __shfl_xor(s, 1);
    s += __shfl_xor(s, 2);
    if (part == 0) gs[i * 64 + j] = s * invI[i] * invT[j] * TAU_INV;
}

__global__ __launch_bounds__(64) void g_lse_k(
    const float* __restrict__ gs, float* __restrict__ out)
{
    const int b = blockIdx.x, lane = threadIdx.x;
    const bool is_col = b >= 64;
    const int r = is_col ? b - 64 : b;
    const float v = is_col ? gs[lane * 64 + r] : gs[r * 64 + lane];
    float m = v;
    #pragma unroll
    for (int o = 32; o > 0; o >>= 1) m = fmaxf(m, __shfl_xor(m, o));
    float s = expf(v - m);
    #pragma unroll
    for (int o = 32; o > 0; o >>= 1) s += __shfl_xor(s, o);
    if (lane == 0)
        atomicAdd(out, ((m + logf(s)) - gs[r * 64 + r]) * (0.5f / 64.0f));
}

// inv L2 norm of 256-wide single-bf16 rows
__global__ __launch_bounds__(256) void inv_norm_b16_k(
    const us* __restrict__ x, float* __restrict__ inv)
{
    const int row = blockIdx.x * 4 + (threadIdx.x >> 6);
    const int lane = threadIdx.x & 63;
    ushort4 h = *(const ushort4*)&x[(long long)row * 256 + lane * 4];
    const float x0 = bf2f(h.x), x1 = bf2f(h.y), x2 = bf2f(h.z), x3 = bf2f(h.w);
    float s = x0 * x0 + x1 * x1 + x2 * x2 + x3 * x3;
    #pragma unroll
    for (int o = 32; o > 0; o >>= 1) s += __shfl_xor(s, o);
    if (lane == 0) inv[row] = 1.0f / fmaxf(sqrtf(s), 1e-8f);
}

// ---- merge kernels ----

__global__ __launch_bounds__(256) void minmax_merge_k(
    const float* __restrict__ mnp, const float* __restrict__ mxp,
    float* __restrict__ mn, float* __restrict__ mx)
{
    const int idx = blockIdx.x * 256 + threadIdx.x;
    float lo = 1e30f, hi = -1e30f;
    #pragma unroll
    for (int c = 0; c < 8; ++c) {
        lo = fminf(lo, mnp[(long long)idx * 8 + c]);
        hi = fmaxf(hi, mxp[(long long)idx * 8 + c]);
    }
    mn[idx] = lo; mx[idx] = hi;
}

__global__ __launch_bounds__(256) void fine_merge4_k(
    const float* __restrict__ pm, const float* __restrict__ ps,
    const float* __restrict__ diag, float* __restrict__ out)
{
    const int idx = blockIdx.x * 256 + threadIdx.x;
    float m = -1e30f, s = 0.f;
    #pragma unroll
    for (int c = 0; c < 4; ++c) {
        const float cm = pm[(long long)idx * 4 + c], cs = ps[(long long)idx * 4 + c];
        const float nm = fmaxf(m, cm);
        s = s * expf(m - nm) + cs * expf(cm - nm);
        m = nm;
    }
    const float contrib = (m + logf(s)) - diag[idx];
    __shared__ float red[256];
    red[threadIdx.x] = contrib;
    __syncthreads();
    for (int w = 128; w > 0; w >>= 1) {
        if (threadIdx.x < w) red[threadIdx.x] += red[threadIdx.x + w];
        __syncthreads();
    }
    if (threadIdx.x == 0) atomicAdd(out, red[0] * (0.5f / (64.0f * 512.0f)));
}

extern "C" void kernel_launch(void* const* d_in, const int* in_sizes, int n_in,
                              void* d_out, int out_size, void* d_ws, size_t ws_size,
                              hipStream_t stream)
{
    const float* img  = (const float*)d_in[0];
    const float* text = (const float*)d_in[1];
    const float* Wv   = (const float*)d_in[2];
    const float* bv   = (const float*)d_in[3];
    const float* Wt   = (const float*)d_in[4];
    const float* bt   = (const float*)d_in[5];
    float* out = (float*)d_out;
    char* ws = (char*)d_ws;

    us* patches = (us*)(ws + 0);              // 33,554,432 B
    us* tokens  = (us*)(ws + 33554432);       // 16,777,216 B
    us* simT    = (us*)(ws + 50331648);       // 67,108,864 B  ([b][s][p])
    us* lgve    = (us*)(ws + 117440512);      // 16,777,216 B
    char* st = ws + 134217728;
    float* mean_img  = (float*)(st + 0);
    float* mean_text = (float*)(st + 65536);
    float* mean_pat  = (float*)(st + 131072);
    float* mean_tok  = (float*)(st + 196608);
    float* g_img     = (float*)(st + 262144);
    float* g_txt     = (float*)(st + 327680);
    float* textpart  = (float*)(st + 393216);
    float* mnp       = (float*)(st + 917504);   // 1 MB
    float* mxp       = (float*)(st + 1966080);  // 1 MB
    float* mnv       = (float*)(st + 3014656);
    float* mxv       = (float*)(st + 3145728);
    float* inv_l     = (float*)(st + 3276800);
    float* inv_t     = (float*)(st + 3407872);
    us* Wvh = (us*)(st + 3538944);
    us* Wvl = (us*)(st + 3670016);
    us* Wth = (us*)(st + 3801088);
    us* Wtl = (us*)(st + 3932160);
    float* inv_gi  = (float*)(st + 4063232);
    float* inv_gt  = (float*)(st + 4063744);
    float* g_simbf = (float*)(st + 4064256);
    float* pm_row  = (float*)(st + 4194304);   // 512 KB (4 partials/row)
    float* ps_row  = (float*)(st + 4718592);   // 512 KB
    float* pm_col  = (float*)(st + 5242880);   // 512 KB
    float* ps_col  = (float*)(st + 5767168);   // 512 KB
    float* diag    = (float*)(st + 6291456);   // 128 KB
    us* patchesT   = (us*)(ws + 140640256);    // 33,554,432 B ([b][d][p])
    // R18 transient planes — region reuse (stream-ordered, no overlap in time):
    // imgTH/imgTL live in simT's slot (consumed by G1, before G4' writes simT);
    // textH/textL live in patchesT's slot (consumed by G2, before transpose_k).
    us* imgTH = (us*)(ws + 50331648);          // 33,554,432 B ([b][p][c])
    us* imgTL = (us*)(ws + 83886080);          // 33,554,432 B
    us* textH = (us*)(ws + 140640256);         // 16,777,216 B ([b][s][d])
    us* textL = (us*)(ws + 157417472);         // 16,777,216 B

    zero_out_k<<<1, 64, 0, stream>>>(out);
    convert_w_k<<<256, 256, 0, stream>>>(Wv, Wt, Wvh, Wvl, Wth, Wtl);

    // Global path (mean commutes with linear). Means run first so the conv
    // prepasses read img/text from L3.
    mean_img_k<<<4096, 256, 0, stream>>>(img, mean_img);
    mean_text_s1<<<dim3(64, 8), 256, 0, stream>>>(text, textpart);
    mean_text_s2<<<64, 256, 0, stream>>>(textpart, mean_text);
    small_adapter_k<<<BB, 256, 0, stream>>>(mean_img, Wv, bv, mean_pat);
    small_adapter_k<<<BB, 256, 0, stream>>>(mean_pat, Wv, bv, g_img);
    small_adapter_k<<<BB, 256, 0, stream>>>(mean_text, Wt, bt, mean_tok);
    small_adapter_k<<<BB, 256, 0, stream>>>(mean_tok, Wt, bt, g_txt);
    inv_norm_f32_k<<<16, 256, 0, stream>>>(g_img, inv_gi);
    inv_norm_f32_k<<<16, 256, 0, stream>>>(g_txt, inv_gt);
    g_sim_k<<<64, 256, 0, stream>>>(g_img, g_txt, inv_gi, inv_gt, g_simbf);
    g_lse_k<<<128, 64, 0, stream>>>(g_simbf, out);

    // R18 prepasses: split (and transpose for img) the f32 inputs once.
    convsplit_img_k<<<dim3(16, 4, BB), 256, 0, stream>>>(img, imgTH, imgTL);
    convsplit_row_k<<<8192, 256, 0, stream>>>(text, textH, textL);

    // G1: patches = img.Wv + bv; R18 full-DMA 4-plane pipeline (NT=128)
    mfma_gemm<OPM_B16_ROW, OPM_B16_ROW, OUT_B16, 1, 128, 0, 8, 3><<<dim3(8, 2, BB), 512, 0, stream>>>(
        imgTH, imgTL, Wvh, Wvl, patches,
        1024, 256, 256, 256, 256, 256,
        524288LL, 0LL, 524288LL, bv, nullptr, nullptr, 0.f, nullptr, nullptr,
        nullptr, nullptr, nullptr, nullptr, nullptr);

    // G2: tokens = text.Wt + bt; R18 full-DMA 4-plane pipeline (NT=128)
    mfma_gemm<OPM_B16_ROW, OPM_B16_ROW, OUT_B16, 1, 128, 0, 8, 3><<<dim3(4, 2, BB), 512, 0, stream>>>(
        textH, textL, Wth, Wtl, tokens,
        512, 256, 256, 256, 256, 256,
        262144LL, 0LL, 262144LL, bt, nullptr, nullptr, 0.f, nullptr, nullptr,
        nullptr, nullptr, nullptr, nullptr, nullptr);

    // R17: patchesT = patches^T (enables DMA staging of G6's B operand)
    transpose_k<<<dim3(16, 4, BB), 256, 0, stream>>>(patches, patchesT);

    // G4': simT = tokens . patches^T, DMA-staged, row-minmax fused.
    mfma_gemm<OPM_B16_ROW, OPM_B16_ROW, OUT_B16, 3, 128, 0, 8, 1><<<dim3(4, 8, BB), 512, 0, stream>>>(
        tokens, nullptr, patches, nullptr, simT,
        512, 1024, 256, 256, 256, 1024,
        262144LL, 524288LL, 1048576LL, nullptr, nullptr, nullptr, 0.f, nullptr, nullptr,
        mnp, mxp, nullptr, nullptr, nullptr);

    minmax_merge_k<<<128, 256, 0, stream>>>(mnp, mxp, mnv, mxv);

    // G6: lgve = w.patches; hybrid: A = simT reg-staged + weight transform,
    // B = patchesT DMA-staged (dbuf, counted vmcnt).
    mfma_gemm<OPM_WGT_ROW, OPM_B16_COL, OUT_B16, 0, 128, 0, 8, 2><<<dim3(4, 2, BB), 512, 0, stream>>>(
        simT, nullptr, patchesT, nullptr, lgve,
        512, 256, 1024, 1024, 1024, 256,
        1048576LL, 524288LL, 262144LL, nullptr, nullptr, nullptr, 0.f, mnv, mxv,
        nullptr, nullptr, nullptr, nullptr, nullptr);

    inv_norm_b16_k<<<8192, 256, 0, stream>>>(lgve, inv_l);
    inv_norm_b16_k<<<8192, 256, 0, stream>>>(tokens, inv_t);

    // G8: f_sim never materialized; DMA-staged, 4 row + 4 col LSE partials
    mfma_gemm<OPM_B16_ROW, OPM_B16_ROW, OUT_B16, 4, 128, 0, 8, 1><<<dim3(4, 4, BB), 512, 0, stream>>>(
        lgve, nullptr, tokens, nullptr, nullptr,
        512, 512, 256, 256, 256, 512,
        262144LL, 262144LL, 0LL, nullptr, inv_l, inv_t, TAU_INV, nullptr, nullptr,
        pm_row, ps_row, pm_col, ps_col, diag);

    fine_merge4_k<<<128, 256, 0, stream>>>(pm_row, ps_row, diag, out);
    fine_merge4_k<<<128, 256, 0, stream>>>(pm_col, ps_col, diag, out);
}

// Round 9
// 382.076 us; speedup vs baseline: 1.0550x; 1.0550x over previous
//
#include <hip/hip_runtime.h>
#include <math.h>

#define BB   64
#define HWP  1024
#define SS   512
#define DD   256
#define TAU_INV (1.0f/0.07f)
#define SIGMA   (1.0f/1024.0f)

typedef unsigned short us;
typedef __attribute__((ext_vector_type(8))) short short8v;
typedef __attribute__((ext_vector_type(8))) unsigned short ushort8v;
typedef __attribute__((ext_vector_type(4))) float floatx4;

__device__ __forceinline__ float bf2f(us u) {
    return __uint_as_float((unsigned)u << 16);
}
__device__ __forceinline__ us f2bf(float f) {
    unsigned u = __float_as_uint(f);
    u += 0x7FFFu + ((u >> 16) & 1u);
    return (us)(u >> 16);
}
__device__ __forceinline__ void split_bf(float v, us& h, us& l) {
    h = f2bf(v);
    l = f2bf(v - bf2f(h));
}

// R15: HBM->LDS DMA, bypasses VGPRs entirely (regalloc cannot sink it).
__device__ __forceinline__ void dma16(const us* g, us* l) {
    __builtin_amdgcn_global_load_lds(
        (const __attribute__((address_space(1))) unsigned int*)g,
        (__attribute__((address_space(3))) unsigned int*)l, 16, 0, 0);
}

__global__ void zero_out_k(float* out) { if (threadIdx.x == 0) out[0] = 0.0f; }

// =====================  MFMA GEMM  =====================
// C[m,n] = sum_k A(m,k)*B(n,k). Tile 128 x NT, BK=32, 16x16x32 bf16 MFMA.
// R15: G4'/G8 DMA pipeline (global_load_lds, dbuf, counted vmcnt) — worked.
// R17: G6 hybrid DMA (transpose prepass + dma B) — worked.
// R18: G1/G2 full-DMA + convsplit prepasses — REGRESSION (+25us): prepasses
//      cost ~35us HBM for ~16us of GEMM savings. Reverted here.
// R19: all DMA kernels showed MfmaUtil ~15%, HBM <=28% — structure-bound.
//      Cause: 2-deep pipeline's prefetch distance = 1 MFMA phase (~200cy)
//      < HBM latency (~900cy). Fix: depth-3 pipelines.
//      DMA=1: 3 LDS buffers (48KB), steady vmcnt(4) -> distance 2 phases.
//      DMA=2: 3 B-buffers, vmcnt(2); B(t) completion is transitively
//      guaranteed by A(t)'s compiler auto-wait (B(t) issued before A(t)).
enum { OPM_F32_ROW = 0, OPM_F32_COL = 1, OPM_SPL_ROW = 2, OPM_SPL_COL = 3,
       OPM_B16_COL = 4, OPM_B16_ROW = 5, OPM_WGT_COL = 6, OPM_WGT_ROW = 7 };
enum { OUT_F32 = 0, OUT_B16 = 1 };

#define LDSTRIDE 40

template<int MODE, int ROWS, int NW>
struct SRegs {
    static constexpr int RR = ROWS / 128;
    static constexpr bool ISF32 = (MODE == OPM_F32_ROW) || (MODE == OPM_F32_COL);
    ushort8v h[ISF32 ? 1 : RR][2];
    ushort8v l[(MODE == OPM_SPL_ROW) ? RR : 1][2];
    float4   f[ISF32 ? RR : 1][4];
};

// global -> registers (raw data, no conversion math)
template<int MODE, int ROWS, int NW>
__device__ __forceinline__ void stage_load(
    const char* p0, const char* p1, int ld, int row0, int k0, int tid,
    SRegs<MODE, ROWS, NW>& R)
{
    #pragma unroll
    for (int rr = 0; rr < ROWS / 128; ++rr) {
        if constexpr (MODE == OPM_SPL_ROW) {
            const us* ph = (const us*)p0;
            const us* pl = (const us*)p1;
            if constexpr (NW == 4) {
                const int i = rr * 128 + (tid >> 1), ko = (tid & 1) * 16;
                const long long g = (long long)(row0 + i) * ld + k0 + ko;
                R.h[rr][0] = *(const ushort8v*)&ph[g];
                R.h[rr][1] = *(const ushort8v*)&ph[g + 8];
                R.l[rr][0] = *(const ushort8v*)&pl[g];
                R.l[rr][1] = *(const ushort8v*)&pl[g + 8];
            } else {
                const int i = rr * 128 + (tid >> 2), ko = (tid & 3) * 8;
                const long long g = (long long)(row0 + i) * ld + k0 + ko;
                R.h[rr][0] = *(const ushort8v*)&ph[g];
                R.l[rr][0] = *(const ushort8v*)&pl[g];
            }
        } else if constexpr (MODE == OPM_B16_ROW || MODE == OPM_WGT_ROW) {
            const us* ph = (const us*)p0;
            if constexpr (NW == 4) {
                const int i = rr * 128 + (tid >> 1), ko = (tid & 1) * 16;
                const long long g = (long long)(row0 + i) * ld + k0 + ko;
                R.h[rr][0] = *(const ushort8v*)&ph[g];
                R.h[rr][1] = *(const ushort8v*)&ph[g + 8];
            } else {
                const int i = rr * 128 + (tid >> 2), ko = (tid & 3) * 8;
                const long long g = (long long)(row0 + i) * ld + k0 + ko;
                R.h[rr][0] = *(const ushort8v*)&ph[g];
            }
        } else if constexpr (MODE == OPM_F32_ROW) {
            const float* pf = (const float*)p0;
            if constexpr (NW == 4) {
                const int i = rr * 128 + (tid >> 1), ko = (tid & 1) * 16;
                const long long g = (long long)(row0 + i) * ld + k0 + ko;
                #pragma unroll
                for (int c = 0; c < 4; ++c)
                    R.f[rr][c] = *(const float4*)&pf[g + c * 4];
            } else {
                const int i = rr * 128 + (tid >> 2), ko = (tid & 3) * 8;
                const long long g = (long long)(row0 + i) * ld + k0 + ko;
                R.f[rr][0] = *(const float4*)&pf[g];
                R.f[rr][1] = *(const float4*)&pf[g + 4];
            }
        } else if constexpr (MODE == OPM_F32_COL) {
            const float* pf = (const float*)p0;
            if constexpr (NW == 4) {
                const int m = rr * 128 + (tid & 127), kh = (tid >> 7) * 16;
                const long long base = (long long)(k0 + kh) * ld + row0 + m;
                #pragma unroll
                for (int c = 0; c < 4; ++c) {
                    float4 v;
                    v.x = pf[base + (long long)(c * 4 + 0) * ld];
                    v.y = pf[base + (long long)(c * 4 + 1) * ld];
                    v.z = pf[base + (long long)(c * 4 + 2) * ld];
                    v.w = pf[base + (long long)(c * 4 + 3) * ld];
                    R.f[rr][c] = v;
                }
            } else {
                const int m = rr * 128 + (tid & 127), kh = (tid >> 7) * 8;
                const long long base = (long long)(k0 + kh) * ld + row0 + m;
                #pragma unroll
                for (int c = 0; c < 2; ++c) {
                    float4 v;
                    v.x = pf[base + (long long)(c * 4 + 0) * ld];
                    v.y = pf[base + (long long)(c * 4 + 1) * ld];
                    v.z = pf[base + (long long)(c * 4 + 2) * ld];
                    v.w = pf[base + (long long)(c * 4 + 3) * ld];
                    R.f[rr][c] = v;
                }
            }
        } else if constexpr (MODE == OPM_B16_COL) {
            const us* ph = (const us*)p0;
            if constexpr (NW == 4) {
                const int m = rr * 128 + (tid & 127), kh = (tid >> 7) * 16;
                const long long base = (long long)(k0 + kh) * ld + row0 + m;
                #pragma unroll
                for (int kk = 0; kk < 8; ++kk) {
                    R.h[rr][0][kk] = ph[base + (long long)kk * ld];
                    R.h[rr][1][kk] = ph[base + (long long)(kk + 8) * ld];
                }
            } else {
                const int m = rr * 128 + (tid & 127), kh = (tid >> 7) * 8;
                const long long base = (long long)(k0 + kh) * ld + row0 + m;
                #pragma unroll
                for (int kk = 0; kk < 8; ++kk)
                    R.h[rr][0][kk] = ph[base + (long long)kk * ld];
            }
        }
    }
}

// registers -> LDS (conversion / weight math happens here)
template<int MODE, int ROWS, int NW>
__device__ __forceinline__ void stage_store(
    const SRegs<MODE, ROWS, NW>& R, us* ldsH, us* ldsL, int tid, float nlo, float inv)
{
    #pragma unroll
    for (int rr = 0; rr < ROWS / 128; ++rr) {
        if constexpr (MODE == OPM_SPL_ROW) {
            if constexpr (NW == 4) {
                const int i = rr * 128 + (tid >> 1), ko = (tid & 1) * 16;
                *(ushort8v*)&ldsH[i * LDSTRIDE + ko]     = R.h[rr][0];
                *(ushort8v*)&ldsH[i * LDSTRIDE + ko + 8] = R.h[rr][1];
                *(ushort8v*)&ldsL[i * LDSTRIDE + ko]     = R.l[rr][0];
                *(ushort8v*)&ldsL[i * LDSTRIDE + ko + 8] = R.l[rr][1];
            } else {
                const int i = rr * 128 + (tid >> 2), ko = (tid & 3) * 8;
                *(ushort8v*)&ldsH[i * LDSTRIDE + ko] = R.h[rr][0];
                *(ushort8v*)&ldsL[i * LDSTRIDE + ko] = R.l[rr][0];
            }
        } else if constexpr (MODE == OPM_B16_ROW) {
            if constexpr (NW == 4) {
                const int i = rr * 128 + (tid >> 1), ko = (tid & 1) * 16;
                *(ushort8v*)&ldsH[i * LDSTRIDE + ko]     = R.h[rr][0];
                *(ushort8v*)&ldsH[i * LDSTRIDE + ko + 8] = R.h[rr][1];
            } else {
                const int i = rr * 128 + (tid >> 2), ko = (tid & 3) * 8;
                *(ushort8v*)&ldsH[i * LDSTRIDE + ko] = R.h[rr][0];
            }
        } else if constexpr (MODE == OPM_WGT_ROW) {
            const int i = tid >> 2, ko = (tid & 3) * 8;
            us v[8];
            #pragma unroll
            for (int j = 0; j < 8; ++j) {
                const float w0 = fmaf(bf2f(R.h[0][0][j]), inv, nlo);
                v[j] = (w0 < SIGMA) ? (us)0 : f2bf(w0);
            }
            *(ushort8v*)&ldsH[i * LDSTRIDE + ko] = *(const ushort8v*)&v[0];
        } else if constexpr (MODE == OPM_F32_ROW) {
            if constexpr (NW == 4) {
                const int i = rr * 128 + (tid >> 1), ko = (tid & 1) * 16;
                us h16[16], l16a[16];
                #pragma unroll
                for (int c = 0; c < 4; ++c) {
                    float4 v = R.f[rr][c];
                    split_bf(v.x, h16[c*4+0], l16a[c*4+0]);
                    split_bf(v.y, h16[c*4+1], l16a[c*4+1]);
                    split_bf(v.z, h16[c*4+2], l16a[c*4+2]);
                    split_bf(v.w, h16[c*4+3], l16a[c*4+3]);
                }
                *(ushort8v*)&ldsH[i * LDSTRIDE + ko]     = *(const ushort8v*)&h16[0];
                *(ushort8v*)&ldsH[i * LDSTRIDE + ko + 8] = *(const ushort8v*)&h16[8];
                *(ushort8v*)&ldsL[i * LDSTRIDE + ko]     = *(const ushort8v*)&l16a[0];
                *(ushort8v*)&ldsL[i * LDSTRIDE + ko + 8] = *(const ushort8v*)&l16a[8];
            } else {
                const int i = rr * 128 + (tid >> 2), ko = (tid & 3) * 8;
                us h8[8], l8[8];
                #pragma unroll
                for (int c = 0; c < 2; ++c) {
                    float4 v = R.f[rr][c];
                    split_bf(v.x, h8[c*4+0], l8[c*4+0]);
                    split_bf(v.y, h8[c*4+1], l8[c*4+1]);
                    split_bf(v.z, h8[c*4+2], l8[c*4+2]);
                    split_bf(v.w, h8[c*4+3], l8[c*4+3]);
                }
                *(ushort8v*)&ldsH[i * LDSTRIDE + ko] = *(const ushort8v*)&h8[0];
                *(ushort8v*)&ldsL[i * LDSTRIDE + ko] = *(const ushort8v*)&l8[0];
            }
        } else if constexpr (MODE == OPM_F32_COL) {
            if constexpr (NW == 4) {
                const int m = rr * 128 + (tid & 127), kh = (tid >> 7) * 16;
                us vh[16], vl[16];
                #pragma unroll
                for (int c = 0; c < 4; ++c) {
                    float4 v = R.f[rr][c];
                    split_bf(v.x, vh[c*4+0], vl[c*4+0]);
                    split_bf(v.y, vh[c*4+1], vl[c*4+1]);
                    split_bf(v.z, vh[c*4+2], vl[c*4+2]);
                    split_bf(v.w, vh[c*4+3], vl[c*4+3]);
                }
                *(ushort8v*)&ldsH[m * LDSTRIDE + kh]     = *(const ushort8v*)&vh[0];
                *(ushort8v*)&ldsH[m * LDSTRIDE + kh + 8] = *(const ushort8v*)&vh[8];
                *(ushort8v*)&ldsL[m * LDSTRIDE + kh]     = *(const ushort8v*)&vl[0];
                *(ushort8v*)&ldsL[m * LDSTRIDE + kh + 8] = *(const ushort8v*)&vl[8];
            } else {
                const int m = rr * 128 + (tid & 127), kh = (tid >> 7) * 8;
                us vh[8], vl[8];
                #pragma unroll
                for (int c = 0; c < 2; ++c) {
                    float4 v = R.f[rr][c];
                    split_bf(v.x, vh[c*4+0], vl[c*4+0]);
                    split_bf(v.y, vh[c*4+1], vl[c*4+1]);
                    split_bf(v.z, vh[c*4+2], vl[c*4+2]);
                    split_bf(v.w, vh[c*4+3], vl[c*4+3]);
                }
                *(ushort8v*)&ldsH[m * LDSTRIDE + kh] = *(const ushort8v*)&vh[0];
                *(ushort8v*)&ldsL[m * LDSTRIDE + kh] = *(const ushort8v*)&vl[0];
            }
        } else if constexpr (MODE == OPM_B16_COL) {
            if constexpr (NW == 4) {
                const int m = rr * 128 + (tid & 127), kh = (tid >> 7) * 16;
                us v[16];
                #pragma unroll
                for (int kk = 0; kk < 16; ++kk)
                    v[kk] = (kk < 8) ? R.h[rr][0][kk & 7] : R.h[rr][1][kk & 7];
                *(ushort8v*)&ldsH[m * LDSTRIDE + kh]     = *(const ushort8v*)&v[0];
                *(ushort8v*)&ldsH[m * LDSTRIDE + kh + 8] = *(const ushort8v*)&v[8];
            } else {
                const int m = rr * 128 + (tid & 127), kh = (tid >> 7) * 8;
                *(ushort8v*)&ldsH[m * LDSTRIDE + kh] = R.h[rr][0];
            }
        }
    }
}

template<int AMODE, int BMODE, int OMODE, int EPI, int NT, int PREF, int NW, int DMA>
__global__ __launch_bounds__(NW * 64) void mfma_gemm(
    const void* A0, const void* A1, const void* B0, const void* B1, void* C0,
    int M, int N, int K, int lda, int ldb, int ldc,
    long long sA, long long sB, long long sC,
    const float* __restrict__ bias, const float* __restrict__ invm,
    const float* __restrict__ invn, float scale,
    const float* __restrict__ wlo, const float* __restrict__ whi,
    float* __restrict__ aux0, float* __restrict__ aux1,
    float* __restrict__ aux2, float* __restrict__ aux3, float* __restrict__ aux4)
{
    constexpr bool ASPL = (AMODE <= OPM_SPL_COL);
    constexpr bool BSPL = (BMODE <= OPM_SPL_COL);
    constexpr int NF = NT / 16;
    constexpr int MI = 8 / NW;         // 16-row frags per wave (2 @NW4, 1 @NW8)
    constexpr int RPW = 128 / NW;      // rows per wave
    __shared__ __align__(16) us Ah[(DMA == 1) ? 8 : 128 * LDSTRIDE];
    __shared__ __align__(16) us Al[(!DMA && ASPL) ? 128 * LDSTRIDE : 8];
    __shared__ __align__(16) us Bh[DMA ? 8 : NT * LDSTRIDE];
    __shared__ __align__(16) us Bl[(!DMA && BSPL) ? NT * LDSTRIDE : 8];
    __shared__ __align__(16) us AhD[(DMA == 1) ? 3 * 128 * 32 : 8];  // 3-deep
    __shared__ __align__(16) us BhD[DMA ? 3 * NT * 32 : 8];          // 3-deep
    __shared__ float redm[(EPI == 4) ? NW * NT : 1];
    __shared__ float reds[(EPI == 4) ? NW * NT : 1];

    const int tid = threadIdx.x;
    const int w = tid >> 6, lane = tid & 63;
    const int quad = lane >> 4, l16 = lane & 15;

    // XCD-chunked bijective swizzle (nwg % 8 == 0 for all grids here).
    int bx = blockIdx.x, by = blockIdx.y, bz = blockIdx.z;
    {
        const int nbx = gridDim.x, nby = gridDim.y, nbz = gridDim.z;
        const int nwg = nbx * nby * nbz;
        if ((nwg & 7) == 0) {
            const int hw = bx + nbx * (by + nby * bz);
            const int cpx = nwg >> 3;
            int wk = (hw & 7) * cpx + (hw >> 3);
            bx = wk % nbx; wk /= nbx;
            by = wk % nby; bz = wk / nby;
        }
    }

    const int m0 = bx * 128, n0 = by * NT;
    const int b = bz;

    const char* Ab0 = (const char*)A0 + (long long)b * sA;
    const char* Ab1 = A1 ? (const char*)A1 + (long long)b * sA : nullptr;
    const char* Bb0 = (const char*)B0 + (long long)b * sB;
    const char* Bb1 = B1 ? (const char*)B1 + (long long)b * sB : nullptr;

    floatx4 acc[MI][NF];
    #pragma unroll
    for (int mi = 0; mi < MI; ++mi)
        #pragma unroll
        for (int ni = 0; ni < NF; ++ni)
            acc[mi][ni] = (floatx4){0.f, 0.f, 0.f, 0.f};

    if constexpr (DMA == 1) {
        // ===== R15a + R19: DMA-staged pipeline (ROW/ROW), depth 3 ===========
        const us* Abu = (const us*)Ab0;
        const us* Bbu = (const us*)Bb0;
        const int drow = 16 * w + (lane >> 2);
        const int dcol = (lane & 3) * 8;
        const us* aS = Abu + (long long)(m0 + drow) * lda + dcol;
        const us* bS = Bbu + (long long)(n0 + drow) * ldb + dcol;
        us* aD = &AhD[0] + 512 * w;
        us* bD = &BhD[0] + 512 * w;
        const int NTL = K >> 5;

        dma16(aS,      aD);                dma16(bS,      bD);
        dma16(aS + 32, aD + 128 * 32);     dma16(bS + 32, bD + NT * 32);
        dma16(aS + 64, aD + 2 * 128 * 32); dma16(bS + 64, bD + 2 * NT * 32);

        int cur = 0;
        for (int t = 0; t < NTL; ++t) {
            if (t + 1 >= NTL)      asm volatile("s_waitcnt vmcnt(0)" ::: "memory");
            else if (t + 2 >= NTL) asm volatile("s_waitcnt vmcnt(2)" ::: "memory");
            else                   asm volatile("s_waitcnt vmcnt(4)" ::: "memory");
            __builtin_amdgcn_s_barrier();
            asm volatile("" ::: "memory");

            {
                const us* Ac = &AhD[cur * 128 * 32];
                const us* Bc = &BhD[cur * NT * 32];
                short8v ah = *(const short8v*)&Ac[(16 * w + l16) * 32 + quad * 8];
                #pragma unroll
                for (int ni = 0; ni < NF; ++ni) {
                    short8v bh = *(const short8v*)&Bc[(16 * ni + l16) * 32 + quad * 8];
                    acc[0][ni] = __builtin_amdgcn_mfma_f32_16x16x32_bf16(ah, bh, acc[0][ni], 0, 0, 0);
                }
            }

            asm volatile("" ::: "memory");
            __builtin_amdgcn_s_barrier();
            if (t + 3 < NTL) {
                const long long off = (long long)(t + 3) * 32;
                dma16(aS + off, aD + cur * 128 * 32);
                dma16(bS + off, bD + cur * NT * 32);
            }
            cur = (cur == 2) ? 0 : cur + 1;
        }
    } else if constexpr (DMA == 2) {
        // ===== R17 + R19: hybrid — A reg-staged (WGT), B DMA depth 3 ========
        // B(t) completion is transitively guaranteed: B(t) is issued before
        // A(t), and A(t)'s compiler auto-waitcnt (at the fmaf) drains it.
        const us* Abu = (const us*)Ab0;   // simT
        const us* Bbu = (const us*)Bb0;   // patchesT
        const float* wloA = wlo + (long long)b * M;
        const float* whiA = whi + (long long)b * M;
        const int ai = tid >> 2, ako = (tid & 3) * 8;
        const float lo = wloA[m0 + ai];
        const float invA = 1.0f / (whiA[m0 + ai] - lo + 1e-8f);
        const float nloA = -lo * invA;

        const int rB = 16 * w + (lane >> 2);
        const us* bS = Bbu + (long long)(n0 + rB) * ldb + (lane & 3) * 8;
        us* bD = &BhD[0] + 512 * w;
        const long long aRow = (long long)(m0 + ai) * lda + ako;
        const int NTL = K >> 5;

        dma16(bS, bD);                                   // B(0) first
        ushort8v ra = *(const ushort8v*)&Abu[aRow];      // A(0)
        dma16(bS + 32, bD + NT * 32);                    // B(1)
        dma16(bS + 64, bD + 2 * NT * 32);                // B(2)

        int cur = 0;
        for (int t = 0; t < NTL; ++t) {
            us v[8];
            #pragma unroll
            for (int j = 0; j < 8; ++j) {
                const float w0 = fmaf(bf2f(ra[j]), invA, nloA);
                v[j] = (w0 < SIGMA) ? (us)0 : f2bf(w0);
            }
            *(ushort8v*)&Ah[ai * LDSTRIDE + ako] = *(const ushort8v*)&v[0];
            if (t + 1 == NTL)
                asm volatile("s_waitcnt vmcnt(0) lgkmcnt(0)" ::: "memory");
            else
                asm volatile("s_waitcnt vmcnt(2) lgkmcnt(0)" ::: "memory");
            __builtin_amdgcn_s_barrier();

            if (t + 1 < NTL)
                ra = *(const ushort8v*)&Abu[aRow + (long long)(t + 1) * 32];

            {
                const us* Bc = &BhD[cur * NT * 32];
                short8v ah = *(const short8v*)&Ah[(16 * w + l16) * LDSTRIDE + quad * 8];
                #pragma unroll
                for (int ni = 0; ni < NF; ++ni) {
                    short8v bh = *(const short8v*)&Bc[(16 * ni + l16) * 32 + quad * 8];
                    acc[0][ni] = __builtin_amdgcn_mfma_f32_16x16x32_bf16(ah, bh, acc[0][ni], 0, 0, 0);
                }
            }
            asm volatile("" ::: "memory");
            __builtin_amdgcn_s_barrier();
            if (t + 3 < NTL)
                dma16(bS + (long long)(t + 3) * 32, bD + cur * NT * 32);
            cur = (cur == 2) ? 0 : cur + 1;
        }
    } else {
        // ================= reg-staged path (G1/G2) =========================
        float nloA = 0.f, invA = 0.f;
        if constexpr (AMODE == OPM_WGT_ROW) {
            const float* wloA = wlo + (long long)b * M;
            const float* whiA = whi + (long long)b * M;
            const int row = m0 + (tid >> 2);
            const float lo = wloA[row];
            invA = 1.0f / (whiA[row] - lo + 1e-8f);
            nloA = -lo * invA;
        }

        SRegs<AMODE, 128, NW> RA0, RA1;
        SRegs<BMODE, NT, NW>  RB0, RB1;
        if constexpr (PREF) {
            stage_load<AMODE, 128, NW>(Ab0, Ab1, lda, m0, 0, tid, RA0);
            stage_load<BMODE, NT, NW>(Bb0, Bb1, ldb, n0, 0, tid, RB0);
            stage_load<AMODE, 128, NW>(Ab0, Ab1, lda, m0, 32, tid, RA1);
            stage_load<BMODE, NT, NW>(Bb0, Bb1, ldb, n0, 32, tid, RB1);
        }

        auto do_mfma = [&]() {
            short8v ah[MI], al[MI];
            #pragma unroll
            for (int mi = 0; mi < MI; ++mi) {
                const int r = (RPW * w + 16 * mi + l16) * LDSTRIDE + quad * 8;
                ah[mi] = *(const short8v*)&Ah[r];
                if constexpr (ASPL) al[mi] = *(const short8v*)&Al[r];
            }
            #pragma unroll
            for (int ni = 0; ni < NF; ++ni) {
                const int rB = (16 * ni + l16) * LDSTRIDE + quad * 8;
                short8v bh = *(const short8v*)&Bh[rB];
                #pragma unroll
                for (int mi = 0; mi < MI; ++mi)
                    acc[mi][ni] = __builtin_amdgcn_mfma_f32_16x16x32_bf16(ah[mi], bh, acc[mi][ni], 0, 0, 0);
                if constexpr (BSPL) {
                    short8v bl = *(const short8v*)&Bl[rB];
                    #pragma unroll
                    for (int mi = 0; mi < MI; ++mi)
                        acc[mi][ni] = __builtin_amdgcn_mfma_f32_16x16x32_bf16(ah[mi], bl, acc[mi][ni], 0, 0, 0);
                }
                if constexpr (ASPL) {
                    #pragma unroll
                    for (int mi = 0; mi < MI; ++mi)
                        acc[mi][ni] = __builtin_amdgcn_mfma_f32_16x16x32_bf16(al[mi], bh, acc[mi][ni], 0, 0, 0);
                }
            }
        };

#define GEMM_SUBSTEP(RAx, RBx, KCUR, KNEXT)                                    \
    do {                                                                       \
        if constexpr (!PREF) {                                                 \
            stage_load<AMODE, 128, NW>(Ab0, Ab1, lda, m0, (KCUR), tid, RAx);   \
            stage_load<BMODE, NT, NW>(Bb0, Bb1, ldb, n0, (KCUR), tid, RBx);    \
        }                                                                      \
        stage_store<AMODE, 128, NW>(RAx, Ah, Al, tid, nloA, invA);             \
        stage_store<BMODE, NT, NW>(RBx, Bh, Bl, tid, 0.f, 0.f);                \
        if constexpr (PREF) {                                                  \
            asm volatile("s_waitcnt lgkmcnt(0)" ::: "memory");                 \
            __builtin_amdgcn_s_barrier();                                      \
            if ((KNEXT) < K) {                                                 \
                stage_load<AMODE, 128, NW>(Ab0, Ab1, lda, m0, (KNEXT), tid, RAx); \
                stage_load<BMODE, NT, NW>(Bb0, Bb1, ldb, n0, (KNEXT), tid, RBx);  \
            }                                                                  \
        } else {                                                               \
            __syncthreads();                                                   \
        }                                                                      \
        do_mfma();                                                             \
        if constexpr (PREF) {                                                  \
            asm volatile("s_waitcnt lgkmcnt(0)" ::: "memory");                 \
            __builtin_amdgcn_s_barrier();                                      \
        } else {                                                               \
            __syncthreads();                                                   \
        }                                                                      \
    } while (0)

        for (int k0 = 0; k0 < K; k0 += 64) {
            GEMM_SUBSTEP(RA0, RB0, k0, k0 + 64);
            GEMM_SUBSTEP(RA1, RB1, k0 + 32, k0 + 96);
        }
#undef GEMM_SUBSTEP
    }

    if constexpr (EPI != 4) {
        char* Cb0 = (char*)C0 + (long long)b * sC;
        #pragma unroll
        for (int mi = 0; mi < MI; ++mi)
            #pragma unroll
            for (int ni = 0; ni < NF; ++ni)
                #pragma unroll
                for (int r = 0; r < 4; ++r) {
                    const int row = m0 + RPW * w + 16 * mi + quad * 4 + r;
                    const int col = n0 + 16 * ni + l16;
                    float v = acc[mi][ni][r];
                    if constexpr (EPI == 1) v += bias[col];
                    const long long idx = (long long)row * ldc + col;
                    if constexpr (OMODE == OUT_F32) ((float*)Cb0)[idx] = v;
                    else                            ((us*)Cb0)[idx] = f2bf(v);
                }
    }

    if constexpr (EPI == 3) {
        // ROW min/max of bf16-rounded stored values (C is simT[s][p]).
        #pragma unroll
        for (int r = 0; r < 4; ++r) {
            const int grow = m0 + RPW * w + quad * 4 + r;
            float lo = 1e30f, hi = -1e30f;
            #pragma unroll
            for (int ni = 0; ni < NF; ++ni) {
                const float vr = bf2f(f2bf(acc[0][ni][r]));
                lo = fminf(lo, vr); hi = fmaxf(hi, vr);
            }
            lo = fminf(lo, __shfl_xor(lo, 1)); hi = fmaxf(hi, __shfl_xor(hi, 1));
            lo = fminf(lo, __shfl_xor(lo, 2)); hi = fmaxf(hi, __shfl_xor(hi, 2));
            lo = fminf(lo, __shfl_xor(lo, 4)); hi = fmaxf(hi, __shfl_xor(hi, 4));
            lo = fminf(lo, __shfl_xor(lo, 8)); hi = fmaxf(hi, __shfl_xor(hi, 8));
            if (l16 == 0) {
                const long long o = ((long long)b * M + grow) * 8 + by;
                aux0[o] = lo; aux1[o] = hi;
            }
        }
    }

    if constexpr (EPI == 4) {
        // f_sim never stored: emit row/col LSE partials + diagonal.
        float bn[NF];
        #pragma unroll
        for (int ni = 0; ni < NF; ++ni)
            bn[ni] = invn[(long long)b * N + n0 + 16 * ni + l16] * scale;
        float amv[MI * 4];
        #pragma unroll
        for (int mi = 0; mi < MI; ++mi)
            #pragma unroll
            for (int r = 0; r < 4; ++r)
                amv[mi * 4 + r] = invm[(long long)b * M + m0 + RPW * w + 16 * mi + quad * 4 + r];

        // row pass
        #pragma unroll
        for (int mi = 0; mi < MI; ++mi)
            #pragma unroll
            for (int r = 0; r < 4; ++r) {
                const int grow = m0 + RPW * w + 16 * mi + quad * 4 + r;
                float vv[NF];
                float rm = -1e30f;
                #pragma unroll
                for (int ni = 0; ni < NF; ++ni) {
                    const float v = acc[mi][ni][r] * amv[mi * 4 + r] * bn[ni];
                    vv[ni] = v;
                    rm = fmaxf(rm, v);
                    if (grow == n0 + 16 * ni + l16)
                        aux4[(long long)b * M + grow] = v;
                }
                #pragma unroll
                for (int o = 8; o > 0; o >>= 1) rm = fmaxf(rm, __shfl_xor(rm, o));
                float rs = 0.f;
                #pragma unroll
                for (int ni = 0; ni < NF; ++ni) rs += expf(vv[ni] - rm);
                #pragma unroll
                for (int o = 8; o > 0; o >>= 1) rs += __shfl_xor(rs, o);
                if (l16 == 0) {
                    const long long o = ((long long)b * M + grow) * 4 + by;
                    aux0[o] = rm; aux1[o] = rs;
                }
            }

        // col pass
        #pragma unroll
        for (int ni = 0; ni < NF; ++ni) {
            float va[MI * 4];
            float cm = -1e30f;
            #pragma unroll
            for (int mi = 0; mi < MI; ++mi)
                #pragma unroll
                for (int r = 0; r < 4; ++r) {
                    const float v = acc[mi][ni][r] * amv[mi * 4 + r] * bn[ni];
                    va[mi * 4 + r] = v;
                    cm = fmaxf(cm, v);
                }
            cm = fmaxf(cm, __shfl_xor(cm, 16));
            cm = fmaxf(cm, __shfl_xor(cm, 32));
            float cs = 0.f;
            #pragma unroll
            for (int j = 0; j < MI * 4; ++j) cs += expf(va[j] - cm);
            cs += __shfl_xor(cs, 16);
            cs += __shfl_xor(cs, 32);
            if (quad == 0) {
                redm[w * NT + 16 * ni + l16] = cm;
                reds[w * NT + 16 * ni + l16] = cs;
            }
        }
        __syncthreads();
        if (tid < NT) {
            float m = -1e30f, s = 0.f;
            #pragma unroll
            for (int w4 = 0; w4 < NW; ++w4) {
                const float cm = redm[w4 * NT + tid], cs = reds[w4 * NT + tid];
                const float nm = fmaxf(m, cm);
                s = s * expf(m - nm) + cs * expf(cm - nm);
                m = nm;
            }
            const long long o = ((long long)b * N + n0 + tid) * 4 + bx;
            aux2[o] = m; aux3[o] = s;
        }
    }
}

// =====================  small kernels  =====================

// R17: patchesT[b][d][p] = patches[b][p][d]; 64x64 LDS tiles.
__global__ __launch_bounds__(256) void transpose_k(
    const us* __restrict__ src, us* __restrict__ dst)
{
    __shared__ us t[64][66];
    const int b = blockIdx.z;
    const int p0 = blockIdx.x * 64, d0 = blockIdx.y * 64;
    const us* s = src + (long long)b * 262144;
    us* d = dst + (long long)b * 262144;
    const int r = threadIdx.x >> 3, c8 = (threadIdx.x & 7) * 8;
    #pragma unroll
    for (int h = 0; h < 64; h += 32)
        *(ushort8v*)&t[r + h][c8] =
            *(const ushort8v*)&s[(long long)(p0 + r + h) * 256 + d0 + c8];
    __syncthreads();
    #pragma unroll
    for (int h = 0; h < 64; h += 32) {
        us v[8];
        #pragma unroll
        for (int j = 0; j < 8; ++j) v[j] = t[c8 + j][r + h];
        *(ushort8v*)&d[(long long)(d0 + r + h) * 1024 + p0 + c8] =
            *(const ushort8v*)&v[0];
    }
}

__global__ __launch_bounds__(256) void convert_w_k(
    const float* Wv, const float* Wt, us* Wvh, us* Wvl, us* Wth, us* Wtl)
{
    const int i = blockIdx.x * 256 + threadIdx.x;
    split_bf(Wv[i], Wvh[i], Wvl[i]);
    split_bf(Wt[i], Wth[i], Wtl[i]);
}

__global__ __launch_bounds__(256) void mean_img_k(
    const float* __restrict__ img, float* __restrict__ mimg)
{
    const int row = blockIdx.x * 4 + (threadIdx.x >> 6);
    const int lane = threadIdx.x & 63;
    const float* p = img + (long long)row * 1024;
    float s = 0.f;
    #pragma unroll
    for (int c = 0; c < 4; ++c) {
        float4 v = *(const float4*)&p[(c * 64 + lane) * 4];
        s += v.x + v.y + v.z + v.w;
    }
    #pragma unroll
    for (int o = 32; o > 0; o >>= 1) s += __shfl_xor(s, o);
    if (lane == 0) mimg[row] = s * (1.0f / 1024.0f);
}

__global__ __launch_bounds__(256) void mean_text_s1(
    const float* __restrict__ text, float* __restrict__ part)
{
    const int b = blockIdx.x, ch = blockIdx.y, k = threadIdx.x;
    const float* p = text + ((long long)b * 512 + ch * 64) * 256 + k;
    float s = 0.f;
    for (int r = 0; r < 64; ++r) s += p[r * 256];
    part[(b * 8 + ch) * 256 + k] = s;
}
__global__ __launch_bounds__(256) void mean_text_s2(
    const float* __restrict__ part, float* __restrict__ mt)
{
    const int b = blockIdx.x, k = threadIdx.x;
    float s = 0.f;
    for (int c = 0; c < 8; ++c) s += part[(b * 8 + c) * 256 + k];
    mt[b * 256 + k] = s * (1.0f / 512.0f);
}

__global__ __launch_bounds__(256) void small_adapter_k(
    const float* __restrict__ x, const float* __restrict__ W,
    const float* __restrict__ bias, float* __restrict__ y)
{
    const int b = blockIdx.x, d = threadIdx.x;
    __shared__ float xs[256];
    xs[d] = x[b * 256 + d];
    __syncthreads();
    const float4* w = (const float4*)(W + (long long)d * 256);
    const float4* xv = (const float4*)xs;
    float s = bias[d];
    #pragma unroll 8
    for (int k = 0; k < 64; ++k) {
        const float4 a = xv[k], ww = w[k];
        s += a.x * ww.x + a.y * ww.y + a.z * ww.z + a.w * ww.w;
    }
    y[b * 256 + d] = s;
}

// ---- parallelized global loss ----

__global__ __launch_bounds__(256) void inv_norm_f32_k(
    const float* __restrict__ x, float* __restrict__ inv)
{
    const int row = blockIdx.x * 4 + (threadIdx.x >> 6);
    const int lane = threadIdx.x & 63;
    float4 v = *(const float4*)&x[(long long)row * 256 + lane * 4];
    float s = v.x * v.x + v.y * v.y + v.z * v.z + v.w * v.w;
    #pragma unroll
    for (int o = 32; o > 0; o >>= 1) s += __shfl_xor(s, o);
    if (lane == 0) inv[row] = 1.0f / fmaxf(sqrtf(s), 1e-8f);
}

__global__ __launch_bounds__(256) void g_sim_k(
    const float* __restrict__ gi, const float* __restrict__ gt,
    const float* __restrict__ invI, const float* __restrict__ invT,
    float* __restrict__ gs)
{
    const int i = blockIdx.x, t = threadIdx.x;
    const int j = t >> 2, part = t & 3;
    __shared__ float a[256];
    a[t] = gi[i * 256 + t];
    __syncthreads();
    const float* bp = gt + (long long)j * 256 + part * 64;
    const float* ap = a + part * 64;
    float s = 0.f;
    #pragma unroll 16
    for (int k = 0; k < 64; ++k) s += ap[k] * bp[k];
    s += __shfl_xor(s, 1);
    s += __shfl_xor(s, 2);
    if (part == 0) gs[i * 64 + j] = s * invI[i] * invT[j] * TAU_INV;
}

__global__ __launch_bounds__(64) void g_lse_k(
    const float* __restrict__ gs, float* __restrict__ out)
{
    const int b = blockIdx.x, lane = threadIdx.x;
    const bool is_col = b >= 64;
    const int r = is_col ? b - 64 : b;
    const float v = is_col ? gs[lane * 64 + r] : gs[r * 64 + lane];
    float m = v;
    #pragma unroll
    for (int o = 32; o > 0; o >>= 1) m = fmaxf(m, __shfl_xor(m, o));
    float s = expf(v - m);
    #pragma unroll
    for (int o = 32; o > 0; o >>= 1) s += __shfl_xor(s, o);
    if (lane == 0)
        atomicAdd(out, ((m + logf(s)) - gs[r * 64 + r]) * (0.5f / 64.0f));
}

// inv L2 norm of 256-wide single-bf16 rows
__global__ __launch_bounds__(256) void inv_norm_b16_k(
    const us* __restrict__ x, float* __restrict__ inv)
{
    const int row = blockIdx.x * 4 + (threadIdx.x >> 6);
    const int lane = threadIdx.x & 63;
    ushort4 h = *(const ushort4*)&x[(long long)row * 256 + lane * 4];
    const float x0 = bf2f(h.x), x1 = bf2f(h.y), x2 = bf2f(h.z), x3 = bf2f(h.w);
    float s = x0 * x0 + x1 * x1 + x2 * x2 + x3 * x3;
    #pragma unroll
    for (int o = 32; o > 0; o >>= 1) s += __shfl_xor(s, o);
    if (lane == 0) inv[row] = 1.0f / fmaxf(sqrtf(s), 1e-8f);
}

// ---- merge kernels ----

__global__ __launch_bounds__(256) void minmax_merge_k(
    const float* __restrict__ mnp, const float* __restrict__ mxp,
    float* __restrict__ mn, float* __restrict__ mx)
{
    const int idx = blockIdx.x * 256 + threadIdx.x;
    float lo = 1e30f, hi = -1e30f;
    #pragma unroll
    for (int c = 0; c < 8; ++c) {
        lo = fminf(lo, mnp[(long long)idx * 8 + c]);
        hi = fmaxf(hi, mxp[(long long)idx * 8 + c]);
    }
    mn[idx] = lo; mx[idx] = hi;
}

__global__ __launch_bounds__(256) void fine_merge4_k(
    const float* __restrict__ pm, const float* __restrict__ ps,
    const float* __restrict__ diag, float* __restrict__ out)
{
    const int idx = blockIdx.x * 256 + threadIdx.x;
    float m = -1e30f, s = 0.f;
    #pragma unroll
    for (int c = 0; c < 4; ++c) {
        const float cm = pm[(long long)idx * 4 + c], cs = ps[(long long)idx * 4 + c];
        const float nm = fmaxf(m, cm);
        s = s * expf(m - nm) + cs * expf(cm - nm);
        m = nm;
    }
    const float contrib = (m + logf(s)) - diag[idx];
    __shared__ float red[256];
    red[threadIdx.x] = contrib;
    __syncthreads();
    for (int w = 128; w > 0; w >>= 1) {
        if (threadIdx.x < w) red[threadIdx.x] += red[threadIdx.x + w];
        __syncthreads();
    }
    if (threadIdx.x == 0) atomicAdd(out, red[0] * (0.5f / (64.0f * 512.0f)));
}

extern "C" void kernel_launch(void* const* d_in, const int* in_sizes, int n_in,
                              void* d_out, int out_size, void* d_ws, size_t ws_size,
                              hipStream_t stream)
{
    const float* img  = (const float*)d_in[0];
    const float* text = (const float*)d_in[1];
    const float* Wv   = (const float*)d_in[2];
    const float* bv   = (const float*)d_in[3];
    const float* Wt   = (const float*)d_in[4];
    const float* bt   = (const float*)d_in[5];
    float* out = (float*)d_out;
    char* ws = (char*)d_ws;

    us* patches = (us*)(ws + 0);              // 33,554,432 B
    us* tokens  = (us*)(ws + 33554432);       // 16,777,216 B
    us* simT    = (us*)(ws + 50331648);       // 67,108,864 B  ([b][s][p])
    us* lgve    = (us*)(ws + 117440512);      // 16,777,216 B
    char* st = ws + 134217728;
    float* mean_img  = (float*)(st + 0);
    float* mean_text = (float*)(st + 65536);
    float* mean_pat  = (float*)(st + 131072);
    float* mean_tok  = (float*)(st + 196608);
    float* g_img     = (float*)(st + 262144);
    float* g_txt     = (float*)(st + 327680);
    float* textpart  = (float*)(st + 393216);
    float* mnp       = (float*)(st + 917504);   // 1 MB
    float* mxp       = (float*)(st + 1966080);  // 1 MB
    float* mnv       = (float*)(st + 3014656);
    float* mxv       = (float*)(st + 3145728);
    float* inv_l     = (float*)(st + 3276800);
    float* inv_t     = (float*)(st + 3407872);
    us* Wvh = (us*)(st + 3538944);
    us* Wvl = (us*)(st + 3670016);
    us* Wth = (us*)(st + 3801088);
    us* Wtl = (us*)(st + 3932160);
    float* inv_gi  = (float*)(st + 4063232);
    float* inv_gt  = (float*)(st + 4063744);
    float* g_simbf = (float*)(st + 4064256);
    float* pm_row  = (float*)(st + 4194304);   // 512 KB (4 partials/row)
    float* ps_row  = (float*)(st + 4718592);   // 512 KB
    float* pm_col  = (float*)(st + 5242880);   // 512 KB
    float* ps_col  = (float*)(st + 5767168);   // 512 KB
    float* diag    = (float*)(st + 6291456);   // 128 KB
    us* patchesT   = (us*)(ws + 140640256);    // 33,554,432 B ([b][d][p])

    zero_out_k<<<1, 64, 0, stream>>>(out);
    convert_w_k<<<256, 256, 0, stream>>>(Wv, Wt, Wvh, Wvl, Wth, Wtl);

    // Global path (mean commutes with linear)
    mean_img_k<<<4096, 256, 0, stream>>>(img, mean_img);
    mean_text_s1<<<dim3(64, 8), 256, 0, stream>>>(text, textpart);
    mean_text_s2<<<64, 256, 0, stream>>>(textpart, mean_text);
    small_adapter_k<<<BB, 256, 0, stream>>>(mean_img, Wv, bv, mean_pat);
    small_adapter_k<<<BB, 256, 0, stream>>>(mean_pat, Wv, bv, g_img);
    small_adapter_k<<<BB, 256, 0, stream>>>(mean_text, Wt, bt, mean_tok);
    small_adapter_k<<<BB, 256, 0, stream>>>(mean_tok, Wt, bt, g_txt);
    inv_norm_f32_k<<<16, 256, 0, stream>>>(g_img, inv_gi);
    inv_norm_f32_k<<<16, 256, 0, stream>>>(g_txt, inv_gt);
    g_sim_k<<<64, 256, 0, stream>>>(g_img, g_txt, inv_gi, inv_gt, g_simbf);
    g_lse_k<<<128, 64, 0, stream>>>(g_simbf, out);

    // G1: patches = img.Wv + bv; R17 config (NW=8 reg-staged, NT=256)
    mfma_gemm<OPM_F32_COL, OPM_SPL_ROW, OUT_B16, 1, 256, 0, 8, 0><<<dim3(8, 1, BB), 512, 0, stream>>>(
        img, nullptr, Wvh, Wvl, patches,
        1024, 256, 256, 1024, 256, 256,
        1048576LL, 0LL, 524288LL, bv, nullptr, nullptr, 0.f, nullptr, nullptr,
        nullptr, nullptr, nullptr, nullptr, nullptr);

    // G2: tokens = text.Wt + bt; R17 config
    mfma_gemm<OPM_F32_ROW, OPM_SPL_ROW, OUT_B16, 1, 256, 0, 8, 0><<<dim3(4, 1, BB), 512, 0, stream>>>(
        text, nullptr, Wth, Wtl, tokens,
        512, 256, 256, 256, 256, 256,
        524288LL, 0LL, 262144LL, bt, nullptr, nullptr, 0.f, nullptr, nullptr,
        nullptr, nullptr, nullptr, nullptr, nullptr);

    // patchesT = patches^T (enables DMA staging of G6's B operand)
    transpose_k<<<dim3(16, 4, BB), 256, 0, stream>>>(patches, patchesT);

    // G4': simT = tokens . patches^T, DMA depth-3, row-minmax fused.
    mfma_gemm<OPM_B16_ROW, OPM_B16_ROW, OUT_B16, 3, 128, 0, 8, 1><<<dim3(4, 8, BB), 512, 0, stream>>>(
        tokens, nullptr, patches, nullptr, simT,
        512, 1024, 256, 256, 256, 1024,
        262144LL, 524288LL, 1048576LL, nullptr, nullptr, nullptr, 0.f, nullptr, nullptr,
        mnp, mxp, nullptr, nullptr, nullptr);

    minmax_merge_k<<<128, 256, 0, stream>>>(mnp, mxp, mnv, mxv);

    // G6: lgve = w.patches; hybrid: A = simT reg-staged + weight transform,
    // B = patchesT DMA depth-3.
    mfma_gemm<OPM_WGT_ROW, OPM_B16_COL, OUT_B16, 0, 128, 0, 8, 2><<<dim3(4, 2, BB), 512, 0, stream>>>(
        simT, nullptr, patchesT, nullptr, lgve,
        512, 256, 1024, 1024, 1024, 256,
        1048576LL, 524288LL, 262144LL, nullptr, nullptr, nullptr, 0.f, mnv, mxv,
        nullptr, nullptr, nullptr, nullptr, nullptr);

    inv_norm_b16_k<<<8192, 256, 0, stream>>>(lgve, inv_l);
    inv_norm_b16_k<<<8192, 256, 0, stream>>>(tokens, inv_t);

    // G8: f_sim never materialized; DMA depth-3, 4 row + 4 col LSE partials
    mfma_gemm<OPM_B16_ROW, OPM_B16_ROW, OUT_B16, 4, 128, 0, 8, 1><<<dim3(4, 4, BB), 512, 0, stream>>>(
        lgve, nullptr, tokens, nullptr, nullptr,
        512, 512, 256, 256, 256, 512,
        262144LL, 262144LL, 0LL, nullptr, inv_l, inv_t, TAU_INV, nullptr, nullptr,
        pm_row, ps_row, pm_col, ps_col, diag);

    fine_merge4_k<<<128, 256, 0, stream>>>(pm_row, ps_row, diag, out);
    fine_merge4_k<<<128, 256, 0, stream>>>(pm_col, ps_col, diag, out);
}